// Round 1
// baseline (915.831 us; speedup 1.0000x reference)
//
#include <hip/hip_runtime.h>
#include <stdint.h>

// ---------------------------------------------------------------------------
// TransformerBlock: 3x (LN -> FC(768,3072) -> GELU -> FC(3072,N)) + attention.
// fp32 in/out, bf16 MFMA compute with fp32 acc.
// Round-5 changes:
//  (1) NEW gemm_256: 8-phase 256x256 pipelined GEMM (8 waves, 128 KiB dbuf
//      LDS, counted vmcnt(4) -- never drained to 0 in the main loop -- raw
//      s_barriers, setprio around MFMA clusters). Targets the ~36% MfmaUtil
//      structural ceiling of the old 2-barrier loop. Used for the 3 FC1
//      GEMMs (N=3072,K=768) and the qkv FC2 (N=2304,K=3072).
//  (2) proj/mlp FC2 (N=768) keep the 128^2 split-K=2 path (256^2 would
//      under-fill the machine at 96 blocks).
// ---------------------------------------------------------------------------

typedef unsigned short u16;
typedef __attribute__((ext_vector_type(8))) short bf16x8;
typedef __attribute__((ext_vector_type(4))) float f32x4;
typedef __attribute__((address_space(1))) unsigned int as1_u32;
typedef __attribute__((address_space(3))) unsigned int as3_u32;

#define PHALF 6291456  // fp32 elements per split-K partial buffer (8192*768)

__device__ __forceinline__ float bf2f(u16 u) {
  union { unsigned int i; float f; } v; v.i = ((unsigned int)u) << 16; return v.f;
}
__device__ __forceinline__ u16 f2bf(float f) {
  union { float f; unsigned int i; } v; v.f = f;
  unsigned int r = v.i + 0x7fffu + ((v.i >> 16) & 1u);  // RNE
  return (u16)(r >> 16);
}
__device__ __forceinline__ float gelu_exact(float x) {
  return 0.5f * x * (1.0f + erff(x * 0.70710678118654752f));
}
__device__ __forceinline__ void async_ld16(const u16* g, u16* l) {
  __builtin_amdgcn_global_load_lds((const as1_u32*)g, (as3_u32*)l, 16, 0, 0);
}

#define BARRIER() do { asm volatile("" ::: "memory"); __builtin_amdgcn_s_barrier(); asm volatile("" ::: "memory"); } while (0)

// ------------------- LayerNorm (per token, C=768) -> bf16 -------------------
// inMode: 0 = bf16 rows, 1 = fp32 rows, 2 = sum of two fp32 partial buffers.
__global__ __launch_bounds__(256) void ln_kernel(const void* __restrict__ xv,
                                                 const float* __restrict__ g,
                                                 const float* __restrict__ be,
                                                 u16* __restrict__ out, int inMode) {
  int token = blockIdx.x, tid = threadIdx.x;
  int wave = tid >> 6, lane = tid & 63;
  float v0, v1, v2;
  if (inMode == 1) {
    const float* row = (const float*)xv + (size_t)token * 768;
    v0 = row[tid]; v1 = row[tid + 256]; v2 = row[tid + 512];
  } else if (inMode == 2) {
    const float* row = (const float*)xv + (size_t)token * 768;
    const float* row2 = row + PHALF;
    v0 = row[tid] + row2[tid];
    v1 = row[tid + 256] + row2[tid + 256];
    v2 = row[tid + 512] + row2[tid + 512];
  } else {
    const u16* row = (const u16*)xv + (size_t)token * 768;
    v0 = bf2f(row[tid]); v1 = bf2f(row[tid + 256]); v2 = bf2f(row[tid + 512]);
  }
  float s = v0 + v1 + v2;
  float q = v0 * v0 + v1 * v1 + v2 * v2;
#pragma unroll
  for (int m = 1; m < 64; m <<= 1) { s += __shfl_xor(s, m); q += __shfl_xor(q, m); }
  __shared__ float red[8];
  if (lane == 0) { red[wave] = s; red[4 + wave] = q; }
  __syncthreads();
  s = red[0] + red[1] + red[2] + red[3];
  q = red[4] + red[5] + red[6] + red[7];
  float mean = s * (1.0f / 768.0f);
  float var  = q * (1.0f / 768.0f) - mean * mean;
  float inv  = rsqrtf(var + 1e-5f);
  u16* o = out + (size_t)token * 768;
  o[tid]       = f2bf((v0 - mean) * inv * g[tid]       + be[tid]);
  o[tid + 256] = f2bf((v1 - mean) * inv * g[tid + 256] + be[tid + 256]);
  o[tid + 512] = f2bf((v2 - mean) * inv * g[tid + 512] + be[tid + 512]);
}

// ------------- fp32 (R x C) -> bf16 transposed (C x R) ----------------------
__global__ __launch_bounds__(256) void transpose_f32_bf16(const float* __restrict__ in,
                                                          u16* __restrict__ out,
                                                          int R, int Cc) {
  __shared__ u16 tile[32][33];
  int c0 = blockIdx.x * 32, r0 = blockIdx.y * 32;
  int tx = threadIdx.x, ty = threadIdx.y;  // 32 x 8
  for (int i = ty; i < 32; i += 8)
    tile[i][tx] = f2bf(in[(size_t)(r0 + i) * Cc + c0 + tx]);
  __syncthreads();
  for (int i = ty; i < 32; i += 8)
    out[(size_t)(c0 + i) * R + r0 + tx] = tile[tx][i];
}

// ------------- V transpose: t(token, 1536 + h*64 + c) -> vt[bh][c][t] -------
__global__ __launch_bounds__(256) void vtrans(const u16* __restrict__ t,
                                              u16* __restrict__ vt) {
  int bh = blockIdx.z, b = bh / 12, h = bh % 12;
  int t0 = blockIdx.x * 32, c0 = blockIdx.y * 32;
  __shared__ u16 tile[32][33];
  int tx = threadIdx.x, ty = threadIdx.y;
  for (int i = ty; i < 32; i += 8)
    tile[i][tx] = t[(size_t)(b * 1024 + t0 + i) * 2304 + 1536 + h * 64 + c0 + tx];
  __syncthreads();
  for (int i = ty; i < 32; i += 8)
    vt[(size_t)bh * 65536 + (size_t)(c0 + i) * 1024 + t0 + tx] = tile[tx][i];
}

// -------------------- add2: out = P0 + P1 (split-K combine) -----------------
__global__ __launch_bounds__(256) void add2_kernel(const float* __restrict__ P,
                                                   float* __restrict__ out) {
  int idx = blockIdx.x * 256 + threadIdx.x;   // f32x4 index, n/4 = 1572864
  const f32x4* p0 = (const f32x4*)P;
  const f32x4* p1 = (const f32x4*)(P + PHALF);
  ((f32x4*)out)[idx] = p0[idx] + p1[idx];
}

// ----------------------------- MFMA GEMM (128^2, split-K path) --------------
#define BM 128
#define BN 128
#define BKK 64

__global__ __launch_bounds__(256, 4) void gemm_mfma(
    const u16* __restrict__ A, int lda,
    const u16* __restrict__ B, int ldb,
    void* __restrict__ C, int ldc,
    int M, int N, int kSplit,
    const float* __restrict__ bias, int act, int cF32, long long cZStride) {
  __shared__ u16 As[BM * BKK];
  __shared__ u16 Bs[BN * BKK];
  int gx = gridDim.x, gy = gridDim.y;
  int bx, by;
  if ((gy & 7) == 0) {
    int lin = blockIdx.y * gx + blockIdx.x;
    int xcd = lin & 7, s = lin >> 3;
    int r = s / gx;
    by = xcd * (gy >> 3) + r;
    bx = s - r * gx;
  } else { bx = blockIdx.x; by = blockIdx.y; }
  int m0 = by * BM, n0 = bx * BN;
  int kOff = blockIdx.z * kSplit;
  int tid = threadIdx.x;
  int wave = tid >> 6, lane = tid & 63;
  int quad = lane >> 4, lo = lane & 15;
  int wr = (wave >> 1) * 64, wc = (wave & 1) * 64;

  f32x4 acc[4][4];
#pragma unroll
  for (int i = 0; i < 4; ++i)
#pragma unroll
    for (int j = 0; j < 4; ++j) acc[i][j] = (f32x4){0.f, 0.f, 0.f, 0.f};

  for (int k0 = kOff; k0 < kOff + kSplit; k0 += BKK) {
#pragma unroll
    for (int p = 0; p < 4; ++p) {
      int idx = tid + p * 256;
      int row = idx >> 3;
      int gch = ((idx & 7) ^ (row & 7)) * 8;
      int ldsOff = (wave * 64 + p * 256) * 8;
      async_ld16(A + (long long)(m0 + row) * lda + k0 + gch, As + ldsOff);
      async_ld16(B + (long long)(n0 + row) * ldb + k0 + gch, Bs + ldsOff);
    }
    __syncthreads();
#pragma unroll
    for (int ks = 0; ks < 2; ++ks) {
      bf16x8 af[4], bf[4];
#pragma unroll
      for (int i = 0; i < 4; ++i) {
        int m = wr + i * 16 + lo;
        int slot = (ks * 4 + quad) ^ (m & 7);
        af[i] = *(const bf16x8*)(As + m * BKK + slot * 8);
      }
#pragma unroll
      for (int j = 0; j < 4; ++j) {
        int n = wc + j * 16 + lo;
        int slot = (ks * 4 + quad) ^ (n & 7);
        bf[j] = *(const bf16x8*)(Bs + n * BKK + slot * 8);
      }
#pragma unroll
      for (int i = 0; i < 4; ++i)
#pragma unroll
        for (int j = 0; j < 4; ++j)
          acc[i][j] = __builtin_amdgcn_mfma_f32_16x16x32_bf16(af[i], bf[j], acc[i][j], 0, 0, 0);
    }
    __syncthreads();
  }

  long long cZ = (long long)blockIdx.z * cZStride;
#pragma unroll
  for (int j = 0; j < 4; ++j) {
    int col = n0 + wc + j * 16 + lo;
    float bv = (bias && blockIdx.z == 0) ? bias[col] : 0.0f;
#pragma unroll
    for (int i = 0; i < 4; ++i) {
      int rb = m0 + wr + i * 16 + quad * 4;
#pragma unroll
      for (int r = 0; r < 4; ++r) {
        int row = rb + r;
        float v = acc[i][j][r] + bv;
        if (act) v = gelu_exact(v);
        long long ci = cZ + (long long)row * ldc + col;
        if (cF32) ((float*)C)[ci] = v;
        else      ((u16*)C)[ci] = f2bf(v);
      }
    }
  }
}

// ----------------------- 8-phase 256x256 pipelined GEMM ---------------------
// A: M x K bf16 row-major (lda=K). B: N x K bf16 row-major (ldb=K).
// C: M x N bf16 (+bias, optional exact GELU). K = T*64, T >= 2, M%256==0,
// N%256==0, gridDim.y%8==0.
// 8 waves (2M x 4N); per-wave output 128x64 = acc[8][4]; LDS 128 KiB dbuf.
// Phase q computes quadrant (g=q>>1 m-half, e=q&1 n-half) = 16 MFMA.
// Half-tile definitions (consumption-aligned):
//   A-half g = LDS rows [g*64,g*64+64) U [128+g*64, 128+g*64+64)
//     (the m-half g of BOTH wave rows) -- read ONLY in phases with that g.
//   B-half e likewise -- read only in phases with that e.
// Stage schedule while computing tile t in buf P (safety in brackets):
//   ph0: A-hi(t+1)->P^1  [other buffer, free since prev group's barrier]
//   ph1: B-hi(t+1)->P^1  [other buffer]
//   ph2: A-lo(t+2)->P    [A-lo(t) reads all done at ph1's trailing barrier]
//   ph3: B-lo(t+2)->P    [B-lo(t) reads (ph0,ph2) done at ph2's barrier]
//   group end: s_waitcnt vmcnt(4)  -> tile t+1 fully resident, the 4 loads
//   of {A-lo,B-lo}(t+2) stay in flight. Never drains to 0 in the loop.
// Out-of-range prefetch tiles are clamped to T-1: the landing region is
// either a dead buffer or receives byte-identical data -> race-free.
__global__ __launch_bounds__(512, 2) void gemm_256(
    const u16* __restrict__ A, int lda,
    const u16* __restrict__ B, int ldb,
    u16* __restrict__ C, int ldc,
    int T,
    const float* __restrict__ bias, int act) {
  __shared__ u16 As[2][256 * 64];
  __shared__ u16 Bs[2][256 * 64];
  int gx = gridDim.x, gy = gridDim.y;
  // XCD row-banded swizzle (gy % 8 == 0 guaranteed by caller)
  int lin = blockIdx.y * gx + blockIdx.x;
  int xcd = lin & 7, sl = lin >> 3;
  int rr = sl / gx;
  int by = xcd * (gy >> 3) + rr;
  int bx = sl - rr * gx;
  int m0 = by * 256, n0 = bx * 256;
  int tid = threadIdx.x;
  int wv = tid >> 6, lane = tid & 63;
  int quad = lane >> 4, lo = lane & 15;
  int wm = (wv >> 2) * 128;   // wave row offset: 0 or 128
  int wn = (wv & 3) * 64;     // wave col offset: 0/64/128/192

  // staging per-thread source geometry: thread tid covers LDS rows
  // {h*64 + (tid>>3)} and {h*64 + 128 + (tid>>3)}, chunk (tid&7) of 8.
  int srow = tid >> 3;                 // 0..63
  int schunk = tid & 7;
  int sx = (schunk ^ (srow & 7)) * 8;  // swizzled source chunk (u16 units)

  // One half-tile stage: 2 global_load_lds x 16B per thread. LDS dest is
  // wave-uniform (lane*16 implicit); row-major [256][64] layout makes chunk
  // c land at byte 16c, so linear dest == swizzled-source involution.
#define STG(Xg, ld, base0, Xs, P, h, kt) do {                                 \
    const u16* g0_ = (Xg) + (long long)((base0) + (h) * 64 + srow) * (ld)     \
                     + (kt) * 64 + sx;                                         \
    async_ld16(g0_,                 &Xs[P][(h) * 4096 + wv * 512]);            \
    async_ld16(g0_ + 128LL * (ld),  &Xs[P][(h) * 4096 + 8192 + wv * 512]);     \
  } while (0)

  f32x4 acc[8][4];
#pragma unroll
  for (int i = 0; i < 8; ++i)
#pragma unroll
    for (int j = 0; j < 4; ++j) acc[i][j] = (f32x4){0.f, 0.f, 0.f, 0.f};

  // prologue: tile 0 fully + {A-lo,B-lo}(1); retire tile 0, keep 4 in flight
  STG(A, lda, m0, As, 0, 0, 0);
  STG(B, ldb, n0, Bs, 0, 0, 0);
  STG(A, lda, m0, As, 0, 1, 0);
  STG(B, ldb, n0, Bs, 0, 1, 0);
  STG(A, lda, m0, As, 1, 0, 1);
  STG(B, ldb, n0, Bs, 1, 0, 1);
  asm volatile("s_waitcnt vmcnt(4)" ::: "memory");
  BARRIER();

#define PHASE(P, g, e, STAGES, TAILWAIT) do {                                 \
    bf16x8 af[2][4], bf[2][2];                                                \
    _Pragma("unroll")                                                          \
    for (int ks = 0; ks < 2; ++ks) {                                           \
      _Pragma("unroll")                                                        \
      for (int i = 0; i < 4; ++i) {                                            \
        int m_ = wm + (g) * 64 + i * 16 + lo;                                  \
        af[ks][i] = *(const bf16x8*)(&As[P][m_ * 64 + (((ks * 4 + quad) ^ (m_ & 7)) * 8)]); \
      }                                                                        \
      _Pragma("unroll")                                                        \
      for (int j = 0; j < 2; ++j) {                                            \
        int n_ = wn + (e) * 32 + j * 16 + lo;                                  \
        bf[ks][j] = *(const bf16x8*)(&Bs[P][n_ * 64 + (((ks * 4 + quad) ^ (n_ & 7)) * 8)]); \
      }                                                                        \
    }                                                                          \
    STAGES;                                                                    \
    BARRIER();                                                                 \
    asm volatile("s_waitcnt lgkmcnt(0)" ::: "memory");                         \
    __builtin_amdgcn_sched_barrier(0);                                         \
    __builtin_amdgcn_s_setprio(1);                                             \
    _Pragma("unroll")                                                          \
    for (int ks = 0; ks < 2; ++ks)                                             \
      _Pragma("unroll")                                                        \
      for (int i = 0; i < 4; ++i)                                              \
        _Pragma("unroll")                                                      \
        for (int j = 0; j < 2; ++j)                                            \
          acc[(g) * 4 + i][(e) * 2 + j] = __builtin_amdgcn_mfma_f32_16x16x32_bf16( \
              af[ks][i], bf[ks][j], acc[(g) * 4 + i][(e) * 2 + j], 0, 0, 0);   \
    __builtin_amdgcn_s_setprio(0);                                             \
    TAILWAIT;                                                                  \
    BARRIER();                                                                 \
  } while (0)

  for (int t = 0; t < T; ++t) {
    int P = t & 1;
    int tn  = (t + 1 < T) ? t + 1 : T - 1;   // clamped prefetch tiles
    int tn2 = (t + 2 < T) ? t + 2 : T - 1;
    PHASE(P, 0, 0, { STG(A, lda, m0, As, P ^ 1, 1, tn); }, );
    PHASE(P, 0, 1, { STG(B, ldb, n0, Bs, P ^ 1, 1, tn); }, );
    PHASE(P, 1, 0, { STG(A, lda, m0, As, P, 0, tn2); }, );
    PHASE(P, 1, 1, { STG(B, ldb, n0, Bs, P, 0, tn2); },
          asm volatile("s_waitcnt vmcnt(4)" ::: "memory"));
  }
  asm volatile("s_waitcnt vmcnt(0)" ::: "memory");
#undef PHASE
#undef STG

  // epilogue: C/D layout col = lane&15, row = quad*4 + r
#pragma unroll
  for (int g = 0; g < 2; ++g)
#pragma unroll
    for (int e = 0; e < 2; ++e)
#pragma unroll
      for (int j = 0; j < 2; ++j) {
        int col = n0 + wn + e * 32 + j * 16 + lo;
        float bv = bias ? bias[col] : 0.0f;
#pragma unroll
        for (int i = 0; i < 4; ++i) {
          int rb = m0 + wm + g * 64 + i * 16 + quad * 4;
#pragma unroll
          for (int r2 = 0; r2 < 4; ++r2) {
            float v = acc[g * 4 + i][e * 2 + j][r2] + bv;
            if (act) v = gelu_exact(v);
            C[(long long)(rb + r2) * ldc + col] = f2bf(v);
          }
        }
      }
}

// --------------- zstats: invZ[t] = 1 / sum_l exp(0.125*K[l].Q[t]) -----------
__global__ __launch_bounds__(256, 2) void zstats(const u16* __restrict__ tb,
                                                 float* __restrict__ zinv) {
  int bh = blockIdx.y, b = bh / 12, h = bh % 12;
  int t0 = blockIdx.x * 128;
  __shared__ u16 Qs[128 * 64];
  __shared__ u16 Ks[128 * 64];
  __shared__ float zred[4][128];
  int tid = threadIdx.x, wave = tid >> 6, lane = tid & 63;
  int quad = lane >> 4, lo = lane & 15;
  const u16* qbase = tb + (size_t)(b * 1024) * 2304 + h * 64;
  const u16* kbase = qbase + 768;

#pragma unroll
  for (int p = 0; p < 4; ++p) {
    int idx = tid + p * 256, row = idx >> 3;
    int ch = ((idx & 7) ^ (row & 7)) * 8;
    async_ld16(qbase + (size_t)(t0 + row) * 2304 + ch, Qs + (wave * 64 + p * 256) * 8);
  }
  float zacc[8];
#pragma unroll
  for (int j = 0; j < 8; ++j) zacc[j] = 0.f;

  for (int lt = 0; lt < 8; ++lt) {
#pragma unroll
    for (int p = 0; p < 4; ++p) {
      int idx = tid + p * 256, row = idx >> 3;
      int ch = ((idx & 7) ^ (row & 7)) * 8;
      async_ld16(kbase + (size_t)(lt * 128 + row) * 2304 + ch, Ks + (wave * 64 + p * 256) * 8);
    }
    __syncthreads();
    f32x4 acc[2][8];
#pragma unroll
    for (int i = 0; i < 2; ++i)
#pragma unroll
      for (int j = 0; j < 8; ++j) acc[i][j] = (f32x4){0.f, 0.f, 0.f, 0.f};
#pragma unroll
    for (int ks = 0; ks < 2; ++ks) {
      bf16x8 af[2], bf[8];
#pragma unroll
      for (int i = 0; i < 2; ++i) {
        int m = wave * 32 + i * 16 + lo;
        int slot = (ks * 4 + quad) ^ (m & 7);
        af[i] = *(const bf16x8*)(Ks + m * 64 + slot * 8);
      }
#pragma unroll
      for (int j = 0; j < 8; ++j) {
        int n = j * 16 + lo;
        int slot = (ks * 4 + quad) ^ (n & 7);
        bf[j] = *(const bf16x8*)(Qs + n * 64 + slot * 8);
      }
#pragma unroll
      for (int i = 0; i < 2; ++i)
#pragma unroll
        for (int j = 0; j < 8; ++j)
          acc[i][j] = __builtin_amdgcn_mfma_f32_16x16x32_bf16(af[i], bf[j], acc[i][j], 0, 0, 0);
    }
#pragma unroll
    for (int j = 0; j < 8; ++j)
#pragma unroll
      for (int i = 0; i < 2; ++i)
#pragma unroll
        for (int r = 0; r < 4; ++r)
          zacc[j] += __expf(acc[i][j][r] * 0.125f);
    __syncthreads();
  }
#pragma unroll
  for (int j = 0; j < 8; ++j) {
    float v = zacc[j];
    v += __shfl_xor(v, 16);
    v += __shfl_xor(v, 32);
    zacc[j] = v;
  }
  if (quad == 0)
#pragma unroll
    for (int j = 0; j < 8; ++j) zred[wave][j * 16 + lo] = zacc[j];
  __syncthreads();
  if (tid < 128) {
    float z = zred[0][tid] + zred[1][tid] + zred[2][tid] + zred[3][tid];
    zinv[(size_t)bh * 1024 + t0 + tid] = 1.0f / z;
  }
}

// --------------- fused attention output -------------------------------------
__global__ __launch_bounds__(256, 2) void attn_out(const u16* __restrict__ tb,
                                                   const u16* __restrict__ vt,
                                                   const float* __restrict__ zinv,
                                                   u16* __restrict__ ao) {
  int bh = blockIdx.y, b = bh / 12, h = bh % 12;
  int l0 = blockIdx.x * 128;
  __shared__ u16 Ks[128 * 64];
  __shared__ u16 Qs[64 * 64];
  __shared__ u16 Vs[64 * 64];
  __shared__ u16 Es[128 * 64];
  int tid = threadIdx.x, wave = tid >> 6, lane = tid & 63;
  int quad = lane >> 4, lo = lane & 15;
  const u16* qbase = tb + (size_t)(b * 1024) * 2304 + h * 64;
  const u16* kbase = qbase + 768;
  const u16* vbase = vt + (size_t)bh * 65536;
  const float* zf = zinv + (size_t)bh * 1024;

#pragma unroll
  for (int p = 0; p < 4; ++p) {
    int idx = tid + p * 256, row = idx >> 3;
    int ch = ((idx & 7) ^ (row & 7)) * 8;
    async_ld16(kbase + (size_t)(l0 + row) * 2304 + ch, Ks + (wave * 64 + p * 256) * 8);
  }
  f32x4 oacc[2][4];
#pragma unroll
  for (int i = 0; i < 2; ++i)
#pragma unroll
    for (int j = 0; j < 4; ++j) oacc[i][j] = (f32x4){0.f, 0.f, 0.f, 0.f};

  for (int tt = 0; tt < 16; ++tt) {
    int t0 = tt * 64;
#pragma unroll
    for (int p = 0; p < 2; ++p) {
      int idx = tid + p * 256, row = idx >> 3;
      int ch = ((idx & 7) ^ (row & 7)) * 8;
      async_ld16(qbase + (size_t)(t0 + row) * 2304 + ch, Qs + (wave * 64 + p * 256) * 8);
      async_ld16(vbase + (size_t)row * 1024 + t0 + ch, Vs + (wave * 64 + p * 256) * 8);
    }
    __syncthreads();
    f32x4 sacc[2][4];
#pragma unroll
    for (int i = 0; i < 2; ++i)
#pragma unroll
      for (int j = 0; j < 4; ++j) sacc[i][j] = (f32x4){0.f, 0.f, 0.f, 0.f};
#pragma unroll
    for (int ks = 0; ks < 2; ++ks) {
      bf16x8 af[2], bq[4];
#pragma unroll
      for (int i = 0; i < 2; ++i) {
        int m = wave * 32 + i * 16 + lo;
        int slot = (ks * 4 + quad) ^ (m & 7);
        af[i] = *(const bf16x8*)(Ks + m * 64 + slot * 8);
      }
#pragma unroll
      for (int j = 0; j < 4; ++j) {
        int n = j * 16 + lo;
        int slot = (ks * 4 + quad) ^ (n & 7);
        bq[j] = *(const bf16x8*)(Qs + n * 64 + slot * 8);
      }
#pragma unroll
      for (int i = 0; i < 2; ++i)
#pragma unroll
        for (int j = 0; j < 4; ++j)
          sacc[i][j] = __builtin_amdgcn_mfma_f32_16x16x32_bf16(af[i], bq[j], sacc[i][j], 0, 0, 0);
    }
#pragma unroll
    for (int j = 0; j < 4; ++j) {
      int t_loc = j * 16 + lo;
      float zi = zf[t0 + t_loc];
      int ch = t_loc >> 3, pos = t_loc & 7;
#pragma unroll
      for (int i = 0; i < 2; ++i)
#pragma unroll
        for (int r = 0; r < 4; ++r) {
          int l_loc = wave * 32 + i * 16 + quad * 4 + r;
          float e = __expf(sacc[i][j][r] * 0.125f) * zi;
          Es[l_loc * 64 + ((ch ^ (l_loc & 7)) * 8 + pos)] = f2bf(e);
        }
    }
#pragma unroll
    for (int ks = 0; ks < 2; ++ks) {
      bf16x8 ae[2], bv[4];
#pragma unroll
      for (int i = 0; i < 2; ++i) {
        int m = wave * 32 + i * 16 + lo;
        int slot = (ks * 4 + quad) ^ (m & 7);
        ae[i] = *(const bf16x8*)(Es + m * 64 + slot * 8);
      }
#pragma unroll
      for (int j = 0; j < 4; ++j) {
        int n = j * 16 + lo;
        int slot = (ks * 4 + quad) ^ (n & 7);
        bv[j] = *(const bf16x8*)(Vs + n * 64 + slot * 8);
      }
#pragma unroll
      for (int i = 0; i < 2; ++i)
#pragma unroll
        for (int j = 0; j < 4; ++j)
          oacc[i][j] = __builtin_amdgcn_mfma_f32_16x16x32_bf16(ae[i], bv[j], oacc[i][j], 0, 0, 0);
    }
    __syncthreads();
  }
#pragma unroll
  for (int j = 0; j < 4; ++j) {
    int c = j * 16 + lo;
#pragma unroll
    for (int i = 0; i < 2; ++i)
#pragma unroll
      for (int r = 0; r < 4; ++r) {
        int l = l0 + wave * 32 + i * 16 + quad * 4 + r;
        ao[(size_t)(b * 1024 + l) * 768 + h * 64 + c] = f2bf(oacc[i][j][r]);
      }
  }
}

// ----------------------------- host orchestration ---------------------------
extern "C" void kernel_launch(void* const* d_in, const int* in_sizes, int n_in,
                              void* d_out, int out_size, void* d_ws, size_t ws_size,
                              hipStream_t stream) {
  const float* x       = (const float*)d_in[0];
  const float* qkv_g   = (const float*)d_in[1];
  const float* qkv_b   = (const float*)d_in[2];
  const float* qkv_W1  = (const float*)d_in[3];
  const float* qkv_b1  = (const float*)d_in[4];
  const float* qkv_W2  = (const float*)d_in[5];
  const float* qkv_b2  = (const float*)d_in[6];
  const float* proj_g  = (const float*)d_in[7];
  const float* proj_b  = (const float*)d_in[8];
  const float* proj_W1 = (const float*)d_in[9];
  const float* proj_b1 = (const float*)d_in[10];
  const float* proj_W2 = (const float*)d_in[11];
  const float* proj_b2 = (const float*)d_in[12];
  const float* mlp_g   = (const float*)d_in[13];
  const float* mlp_b   = (const float*)d_in[14];
  const float* mlp_W1  = (const float*)d_in[15];
  const float* mlp_b1  = (const float*)d_in[16];
  const float* mlp_W2  = (const float*)d_in[17];
  const float* mlp_b2  = (const float*)d_in[18];

  u16* ws  = (u16*)d_ws;               // u16 offsets; ~157 MB total
  u16* xn  = ws;                       // 6291456 (LN out; zinv aliases this)
  u16* tb  = ws + 6291456;             // qkv out 8192x2304
  u16* ao  = ws + 25165824;            // attention out
  u16* yb  = ws + 31457280;            // proj block out
  u16* vt  = ws + 37748736;            // V^T [96][64][1024]
  u16* wt1 = ws + 44040192;            // W1^T bf16
  u16* wt2 = ws + 46399488;            // W2^T bf16
  u16* hS  = ws + 53477376;            // hidden 8192x3072
  float* zinv = (float*)xn;            // 96*1024 floats, aliases dead xn
  float* Pf  = (float*)tb;             // split-K partials 2x8192x768 fp32

  // ---- qkv block ----
  transpose_f32_bf16<<<dim3(96, 24), dim3(32, 8), 0, stream>>>(qkv_W1, wt1, 768, 3072);
  transpose_f32_bf16<<<dim3(72, 96), dim3(32, 8), 0, stream>>>(qkv_W2, wt2, 3072, 2304);
  ln_kernel<<<8192, 256, 0, stream>>>(x, qkv_g, qkv_b, xn, 1);
  gemm_256<<<dim3(12, 32), dim3(512), 0, stream>>>(
      xn, 768, wt1, 768, hS, 3072, 12, qkv_b1, 1);
  gemm_256<<<dim3(9, 32), dim3(512), 0, stream>>>(
      hS, 3072, wt2, 3072, tb, 2304, 48, qkv_b2, 0);

  // ---- attention (fused) ----
  vtrans<<<dim3(32, 2, 96), dim3(32, 8), 0, stream>>>(tb, vt);
  zstats<<<dim3(8, 96), dim3(256), 0, stream>>>(tb, zinv);
  attn_out<<<dim3(8, 96), dim3(256), 0, stream>>>(tb, vt, zinv, ao);

  // ---- proj block ----
  transpose_f32_bf16<<<dim3(96, 24), dim3(32, 8), 0, stream>>>(proj_W1, wt1, 768, 3072);
  transpose_f32_bf16<<<dim3(24, 96), dim3(32, 8), 0, stream>>>(proj_W2, wt2, 3072, 768);
  ln_kernel<<<8192, 256, 0, stream>>>(ao, proj_g, proj_b, xn, 0);
  gemm_256<<<dim3(12, 32), dim3(512), 0, stream>>>(
      xn, 768, wt1, 768, hS, 3072, 12, proj_b1, 1);
  gemm_mfma<<<dim3(6, 64, 2), dim3(256), 0, stream>>>(
      hS, 3072, wt2, 3072, Pf, 768, 8192, 768, 1536, proj_b2, 0, 1, PHALF);

  // ---- mlp block ----
  transpose_f32_bf16<<<dim3(96, 24), dim3(32, 8), 0, stream>>>(mlp_W1, wt1, 768, 3072);
  transpose_f32_bf16<<<dim3(24, 96), dim3(32, 8), 0, stream>>>(mlp_W2, wt2, 3072, 768);
  ln_kernel<<<8192, 256, 0, stream>>>(Pf, mlp_g, mlp_b, xn, 2);  // combines P0+P1
  gemm_256<<<dim3(12, 32), dim3(512), 0, stream>>>(
      xn, 768, wt1, 768, hS, 3072, 12, mlp_b1, 1);
  gemm_mfma<<<dim3(6, 64, 2), dim3(256), 0, stream>>>(
      hS, 3072, wt2, 3072, Pf, 768, 8192, 768, 1536, mlp_b2, 0, 1, PHALF);
  add2_kernel<<<6144, 256, 0, stream>>>(Pf, (float*)d_out);
}

// Round 2
// 804.461 us; speedup vs baseline: 1.1384x; 1.1384x over previous
//
#include <hip/hip_runtime.h>
#include <stdint.h>

// ---------------------------------------------------------------------------
// TransformerBlock: 3x (LN -> FC(768,3072) -> GELU -> FC(3072,N)) + attention.
// fp32 in/out, bf16 MFMA compute with fp32 acc.
// Round-6 changes (fix of round-5's mis-ported 8-phase GEMM):
//  gemm_256 now follows the verified m201 schedule exactly:
//   - 8 phases per GROUP of 2 K-tiles (even tile in buf0, odd in buf1).
//   - Fragment reuse: quadrant order (0,0)(0,1)(1,1)(1,0) per tile; A-frags
//     loaded once per m-half (8 ds_read_b128) and carried across the e-pair;
//     B-h1 carried ph2->ph3; B-h0 reloaded in ph4 (cheap, under MFMA shadow).
//     LDS reads per K-tile: 12/4/8/4 = 28 (was 48) -> phases become
//     MFMA-bound (~515cy) instead of LDS-bound (~900-1600cy).
//   - One half-tile staged per phase; vmcnt(4) only at phases 4 and 8
//     (>=2.5 phases issue-to-wait slack), never drained in the loop.
// ---------------------------------------------------------------------------

typedef unsigned short u16;
typedef __attribute__((ext_vector_type(8))) short bf16x8;
typedef __attribute__((ext_vector_type(4))) float f32x4;
typedef __attribute__((address_space(1))) unsigned int as1_u32;
typedef __attribute__((address_space(3))) unsigned int as3_u32;

#define PHALF 6291456  // fp32 elements per split-K partial buffer (8192*768)

__device__ __forceinline__ float bf2f(u16 u) {
  union { unsigned int i; float f; } v; v.i = ((unsigned int)u) << 16; return v.f;
}
__device__ __forceinline__ u16 f2bf(float f) {
  union { float f; unsigned int i; } v; v.f = f;
  unsigned int r = v.i + 0x7fffu + ((v.i >> 16) & 1u);  // RNE
  return (u16)(r >> 16);
}
__device__ __forceinline__ float gelu_exact(float x) {
  return 0.5f * x * (1.0f + erff(x * 0.70710678118654752f));
}
__device__ __forceinline__ void async_ld16(const u16* g, u16* l) {
  __builtin_amdgcn_global_load_lds((const as1_u32*)g, (as3_u32*)l, 16, 0, 0);
}

#define BARRIER() do { asm volatile("" ::: "memory"); __builtin_amdgcn_s_barrier(); asm volatile("" ::: "memory"); } while (0)

// ------------------- LayerNorm (per token, C=768) -> bf16 -------------------
// inMode: 0 = bf16 rows, 1 = fp32 rows, 2 = sum of two fp32 partial buffers.
__global__ __launch_bounds__(256) void ln_kernel(const void* __restrict__ xv,
                                                 const float* __restrict__ g,
                                                 const float* __restrict__ be,
                                                 u16* __restrict__ out, int inMode) {
  int token = blockIdx.x, tid = threadIdx.x;
  int wave = tid >> 6, lane = tid & 63;
  float v0, v1, v2;
  if (inMode == 1) {
    const float* row = (const float*)xv + (size_t)token * 768;
    v0 = row[tid]; v1 = row[tid + 256]; v2 = row[tid + 512];
  } else if (inMode == 2) {
    const float* row = (const float*)xv + (size_t)token * 768;
    const float* row2 = row + PHALF;
    v0 = row[tid] + row2[tid];
    v1 = row[tid + 256] + row2[tid + 256];
    v2 = row[tid + 512] + row2[tid + 512];
  } else {
    const u16* row = (const u16*)xv + (size_t)token * 768;
    v0 = bf2f(row[tid]); v1 = bf2f(row[tid + 256]); v2 = bf2f(row[tid + 512]);
  }
  float s = v0 + v1 + v2;
  float q = v0 * v0 + v1 * v1 + v2 * v2;
#pragma unroll
  for (int m = 1; m < 64; m <<= 1) { s += __shfl_xor(s, m); q += __shfl_xor(q, m); }
  __shared__ float red[8];
  if (lane == 0) { red[wave] = s; red[4 + wave] = q; }
  __syncthreads();
  s = red[0] + red[1] + red[2] + red[3];
  q = red[4] + red[5] + red[6] + red[7];
  float mean = s * (1.0f / 768.0f);
  float var  = q * (1.0f / 768.0f) - mean * mean;
  float inv  = rsqrtf(var + 1e-5f);
  u16* o = out + (size_t)token * 768;
  o[tid]       = f2bf((v0 - mean) * inv * g[tid]       + be[tid]);
  o[tid + 256] = f2bf((v1 - mean) * inv * g[tid + 256] + be[tid + 256]);
  o[tid + 512] = f2bf((v2 - mean) * inv * g[tid + 512] + be[tid + 512]);
}

// ------------- fp32 (R x C) -> bf16 transposed (C x R) ----------------------
__global__ __launch_bounds__(256) void transpose_f32_bf16(const float* __restrict__ in,
                                                          u16* __restrict__ out,
                                                          int R, int Cc) {
  __shared__ u16 tile[32][33];
  int c0 = blockIdx.x * 32, r0 = blockIdx.y * 32;
  int tx = threadIdx.x, ty = threadIdx.y;  // 32 x 8
  for (int i = ty; i < 32; i += 8)
    tile[i][tx] = f2bf(in[(size_t)(r0 + i) * Cc + c0 + tx]);
  __syncthreads();
  for (int i = ty; i < 32; i += 8)
    out[(size_t)(c0 + i) * R + r0 + tx] = tile[tx][i];
}

// ------------- V transpose: t(token, 1536 + h*64 + c) -> vt[bh][c][t] -------
__global__ __launch_bounds__(256) void vtrans(const u16* __restrict__ t,
                                              u16* __restrict__ vt) {
  int bh = blockIdx.z, b = bh / 12, h = bh % 12;
  int t0 = blockIdx.x * 32, c0 = blockIdx.y * 32;
  __shared__ u16 tile[32][33];
  int tx = threadIdx.x, ty = threadIdx.y;
  for (int i = ty; i < 32; i += 8)
    tile[i][tx] = t[(size_t)(b * 1024 + t0 + i) * 2304 + 1536 + h * 64 + c0 + tx];
  __syncthreads();
  for (int i = ty; i < 32; i += 8)
    vt[(size_t)bh * 65536 + (size_t)(c0 + i) * 1024 + t0 + tx] = tile[tx][i];
}

// -------------------- add2: out = P0 + P1 (split-K combine) -----------------
__global__ __launch_bounds__(256) void add2_kernel(const float* __restrict__ P,
                                                   float* __restrict__ out) {
  int idx = blockIdx.x * 256 + threadIdx.x;   // f32x4 index, n/4 = 1572864
  const f32x4* p0 = (const f32x4*)P;
  const f32x4* p1 = (const f32x4*)(P + PHALF);
  ((f32x4*)out)[idx] = p0[idx] + p1[idx];
}

// ----------------------------- MFMA GEMM (128^2, split-K path) --------------
#define BM 128
#define BN 128
#define BKK 64

__global__ __launch_bounds__(256, 4) void gemm_mfma(
    const u16* __restrict__ A, int lda,
    const u16* __restrict__ B, int ldb,
    void* __restrict__ C, int ldc,
    int M, int N, int kSplit,
    const float* __restrict__ bias, int act, int cF32, long long cZStride) {
  __shared__ u16 As[BM * BKK];
  __shared__ u16 Bs[BN * BKK];
  int gx = gridDim.x, gy = gridDim.y;
  int bx, by;
  if ((gy & 7) == 0) {
    int lin = blockIdx.y * gx + blockIdx.x;
    int xcd = lin & 7, s = lin >> 3;
    int r = s / gx;
    by = xcd * (gy >> 3) + r;
    bx = s - r * gx;
  } else { bx = blockIdx.x; by = blockIdx.y; }
  int m0 = by * BM, n0 = bx * BN;
  int kOff = blockIdx.z * kSplit;
  int tid = threadIdx.x;
  int wave = tid >> 6, lane = tid & 63;
  int quad = lane >> 4, lo = lane & 15;
  int wr = (wave >> 1) * 64, wc = (wave & 1) * 64;

  f32x4 acc[4][4];
#pragma unroll
  for (int i = 0; i < 4; ++i)
#pragma unroll
    for (int j = 0; j < 4; ++j) acc[i][j] = (f32x4){0.f, 0.f, 0.f, 0.f};

  for (int k0 = kOff; k0 < kOff + kSplit; k0 += BKK) {
#pragma unroll
    for (int p = 0; p < 4; ++p) {
      int idx = tid + p * 256;
      int row = idx >> 3;
      int gch = ((idx & 7) ^ (row & 7)) * 8;
      int ldsOff = (wave * 64 + p * 256) * 8;
      async_ld16(A + (long long)(m0 + row) * lda + k0 + gch, As + ldsOff);
      async_ld16(B + (long long)(n0 + row) * ldb + k0 + gch, Bs + ldsOff);
    }
    __syncthreads();
#pragma unroll
    for (int ks = 0; ks < 2; ++ks) {
      bf16x8 af[4], bf[4];
#pragma unroll
      for (int i = 0; i < 4; ++i) {
        int m = wr + i * 16 + lo;
        int slot = (ks * 4 + quad) ^ (m & 7);
        af[i] = *(const bf16x8*)(As + m * BKK + slot * 8);
      }
#pragma unroll
      for (int j = 0; j < 4; ++j) {
        int n = wc + j * 16 + lo;
        int slot = (ks * 4 + quad) ^ (n & 7);
        bf[j] = *(const bf16x8*)(Bs + n * BKK + slot * 8);
      }
#pragma unroll
      for (int i = 0; i < 4; ++i)
#pragma unroll
        for (int j = 0; j < 4; ++j)
          acc[i][j] = __builtin_amdgcn_mfma_f32_16x16x32_bf16(af[i], bf[j], acc[i][j], 0, 0, 0);
    }
    __syncthreads();
  }

  long long cZ = (long long)blockIdx.z * cZStride;
#pragma unroll
  for (int j = 0; j < 4; ++j) {
    int col = n0 + wc + j * 16 + lo;
    float bv = (bias && blockIdx.z == 0) ? bias[col] : 0.0f;
#pragma unroll
    for (int i = 0; i < 4; ++i) {
      int rb = m0 + wr + i * 16 + quad * 4;
#pragma unroll
      for (int r = 0; r < 4; ++r) {
        int row = rb + r;
        float v = acc[i][j][r] + bv;
        if (act) v = gelu_exact(v);
        long long ci = cZ + (long long)row * ldc + col;
        if (cF32) ((float*)C)[ci] = v;
        else      ((u16*)C)[ci] = f2bf(v);
      }
    }
  }
}

// ----------------------- 8-phase 256x256 pipelined GEMM (m201 port) ---------
// A: M x K bf16 row-major (lda=K). B: N x K bf16 row-major (ldb=K).
// C: M x N bf16 (+bias, optional exact GELU). K = T*64, T even >= 2,
// M%256==0, N%256==0, gridDim.y%8==0.
// 8 waves (2M x 4N); per-wave output 128x64 = acc[8][4]; LDS 128 KiB.
// Buffers fixed by K-tile parity: even tiles in buf0, odd in buf1.
// GROUP g covers tiles t0=2g (phases 1-4, buf0) and t1=2g+1 (phases 5-8,
// buf1) with quadrant order (0,0)(0,1)(1,1)(1,0) per tile.
// Fragment loads per tile: ph 12 / 4 / 8 / 4 ds_read_b128 (af carried across
// the e-pair; bf1 carried ph2->ph3; bf0 reloaded ph4 under the MFMA shadow).
// Stage slots (1 half-tile = 2 global_load_lds per phase), derived from
// consumed-after constraints:
//   ph1: A-h1(t1)->buf1      ph2: B-h0(t1)->buf1     [finish tile t1]
//   ph3: A-h0(t0+2)->buf0    ph4: B-h1(t0+2)->buf0
//   ph5: A-h1(t0+2)->buf0    ph6: B-h0(t0+2)->buf0   [tile t0+2 complete]
//   ph7: A-h0(t1+2)->buf1    ph8: B-h1(t1+2)->buf1   [rest next group ph1/2]
// vmcnt(4) at ph4 (tile t1 resident before phases 5-8) and ph8 (tile t0+2
// resident before next group) -- never drained to 0 in the loop.
// Clamped prefetch tiles re-stage identical bytes -> race-free.
__global__ __launch_bounds__(512, 2) void gemm_256(
    const u16* __restrict__ A, int lda,
    const u16* __restrict__ B, int ldb,
    u16* __restrict__ C, int ldc,
    int T,
    const float* __restrict__ bias, int act) {
  __shared__ u16 As[2][256 * 64];
  __shared__ u16 Bs[2][256 * 64];
  int gx = gridDim.x, gy = gridDim.y;
  // XCD row-banded swizzle (gy % 8 == 0 guaranteed by caller)
  int lin = blockIdx.y * gx + blockIdx.x;
  int xcd = lin & 7, sl = lin >> 3;
  int rr = sl / gx;
  int by = xcd * (gy >> 3) + rr;
  int bx = sl - rr * gx;
  int m0 = by * 256, n0 = bx * 256;
  int tid = threadIdx.x;
  int wv = tid >> 6, lane = tid & 63;
  int quad = lane >> 4, lo = lane & 15;
  int wm = (wv >> 2) * 128;   // wave row offset: 0 or 128
  int wn = (wv & 3) * 64;     // wave col offset: 0/64/128/192

  // staging per-thread source geometry: thread tid covers LDS rows
  // {h*64 + (tid>>3)} and {h*64 + 128 + (tid>>3)}, chunk (tid&7) of 8.
  int srow = tid >> 3;                 // 0..63
  int schunk = tid & 7;
  int sx = (schunk ^ (srow & 7)) * 8;  // swizzled source chunk (u16 units)

#define STG(Xg, ld, base0, Xs, P, h, kt) do {                                 \
    const u16* g0_ = (Xg) + (long long)((base0) + (h) * 64 + srow) * (ld)     \
                     + (kt) * 64 + sx;                                         \
    async_ld16(g0_,                 &Xs[P][(h) * 4096 + wv * 512]);            \
    async_ld16(g0_ + 128LL * (ld),  &Xs[P][(h) * 4096 + 8192 + wv * 512]);     \
  } while (0)

  f32x4 acc[8][4];
#pragma unroll
  for (int i = 0; i < 8; ++i)
#pragma unroll
    for (int j = 0; j < 4; ++j) acc[i][j] = (f32x4){0.f, 0.f, 0.f, 0.f};

  bf16x8 af[2][4];   // A frags for current m-half (carried across e-pair)
  bf16x8 bfv[2][2];  // B frags for current e-half

  // prologue: tile 0 complete + {A-h0,B-h1}(1); enter steady state with the
  // same 4-instruction carry the loop maintains (group-0 ph1/ph2 stage the
  // remaining {A-h1,B-h0}(1)).
  STG(A, lda, m0, As, 0, 0, 0);
  STG(B, ldb, n0, Bs, 0, 0, 0);
  STG(A, lda, m0, As, 0, 1, 0);
  STG(B, ldb, n0, Bs, 0, 1, 0);
  STG(A, lda, m0, As, 1, 0, 1);
  STG(B, ldb, n0, Bs, 1, 1, 1);
  asm volatile("s_waitcnt vmcnt(4)" ::: "memory");
  BARRIER();

#define PH(P, g, e, LA, LB, STAGES, TAILWAIT) do {                             \
    if (LA) {                                                                  \
      _Pragma("unroll")                                                        \
      for (int i = 0; i < 4; ++i) {                                            \
        int m_ = wm + (g) * 64 + i * 16 + lo;                                  \
        _Pragma("unroll")                                                      \
        for (int ks = 0; ks < 2; ++ks)                                         \
          af[ks][i] = *(const bf16x8*)(&As[P][m_ * 64 + (((ks * 4 + quad) ^ (m_ & 7)) * 8)]); \
      }                                                                        \
    }                                                                          \
    if (LB) {                                                                  \
      _Pragma("unroll")                                                        \
      for (int j = 0; j < 2; ++j) {                                            \
        int n_ = wn + (e) * 32 + j * 16 + lo;                                  \
        _Pragma("unroll")                                                      \
        for (int ks = 0; ks < 2; ++ks)                                         \
          bfv[ks][j] = *(const bf16x8*)(&Bs[P][n_ * 64 + (((ks * 4 + quad) ^ (n_ & 7)) * 8)]); \
      }                                                                        \
    }                                                                          \
    STAGES;                                                                    \
    BARRIER();                                                                 \
    asm volatile("s_waitcnt lgkmcnt(0)" ::: "memory");                         \
    __builtin_amdgcn_sched_barrier(0);                                         \
    __builtin_amdgcn_s_setprio(1);                                             \
    _Pragma("unroll")                                                          \
    for (int ks = 0; ks < 2; ++ks)                                             \
      _Pragma("unroll")                                                        \
      for (int i = 0; i < 4; ++i)                                              \
        _Pragma("unroll")                                                      \
        for (int j = 0; j < 2; ++j)                                            \
          acc[(g) * 4 + i][(e) * 2 + j] = __builtin_amdgcn_mfma_f32_16x16x32_bf16( \
              af[ks][i], bfv[ks][j], acc[(g) * 4 + i][(e) * 2 + j], 0, 0, 0);  \
    __builtin_amdgcn_s_setprio(0);                                             \
    TAILWAIT;                                                                  \
    BARRIER();                                                                 \
  } while (0)

  int G = T >> 1;
  for (int gq = 0; gq < G; ++gq) {
    int t1 = 2 * gq + 1;
    int c0 = (2 * gq + 2 < T) ? 2 * gq + 2 : T - 2;   // even clamp
    int c1 = (2 * gq + 3 < T) ? 2 * gq + 3 : T - 1;   // odd clamp
    PH(0, 0, 0, 1, 1, STG(A, lda, m0, As, 1, 1, t1), );
    PH(0, 0, 1, 0, 1, STG(B, ldb, n0, Bs, 1, 0, t1), );
    PH(0, 1, 1, 1, 0, STG(A, lda, m0, As, 0, 0, c0), );
    PH(0, 1, 0, 0, 1, STG(B, ldb, n0, Bs, 0, 1, c0),
       asm volatile("s_waitcnt vmcnt(4)" ::: "memory"));
    PH(1, 0, 0, 1, 1, STG(A, lda, m0, As, 0, 1, c0), );
    PH(1, 0, 1, 0, 1, STG(B, ldb, n0, Bs, 0, 0, c0), );
    PH(1, 1, 1, 1, 0, STG(A, lda, m0, As, 1, 0, c1), );
    PH(1, 1, 0, 0, 1, STG(B, ldb, n0, Bs, 1, 1, c1),
       asm volatile("s_waitcnt vmcnt(4)" ::: "memory"));
  }
  asm volatile("s_waitcnt vmcnt(0)" ::: "memory");
#undef PH
#undef STG

  // epilogue: C/D layout col = lane&15, row = quad*4 + r
#pragma unroll
  for (int g = 0; g < 2; ++g)
#pragma unroll
    for (int e = 0; e < 2; ++e)
#pragma unroll
      for (int j = 0; j < 2; ++j) {
        int col = n0 + wn + e * 32 + j * 16 + lo;
        float bv = bias ? bias[col] : 0.0f;
#pragma unroll
        for (int i = 0; i < 4; ++i) {
          int rb = m0 + wm + g * 64 + i * 16 + quad * 4;
#pragma unroll
          for (int r2 = 0; r2 < 4; ++r2) {
            float v = acc[g * 4 + i][e * 2 + j][r2] + bv;
            if (act) v = gelu_exact(v);
            C[(long long)(rb + r2) * ldc + col] = f2bf(v);
          }
        }
      }
}

// --------------- zstats: invZ[t] = 1 / sum_l exp(0.125*K[l].Q[t]) -----------
__global__ __launch_bounds__(256, 2) void zstats(const u16* __restrict__ tb,
                                                 float* __restrict__ zinv) {
  int bh = blockIdx.y, b = bh / 12, h = bh % 12;
  int t0 = blockIdx.x * 128;
  __shared__ u16 Qs[128 * 64];
  __shared__ u16 Ks[128 * 64];
  __shared__ float zred[4][128];
  int tid = threadIdx.x, wave = tid >> 6, lane = tid & 63;
  int quad = lane >> 4, lo = lane & 15;
  const u16* qbase = tb + (size_t)(b * 1024) * 2304 + h * 64;
  const u16* kbase = qbase + 768;

#pragma unroll
  for (int p = 0; p < 4; ++p) {
    int idx = tid + p * 256, row = idx >> 3;
    int ch = ((idx & 7) ^ (row & 7)) * 8;
    async_ld16(qbase + (size_t)(t0 + row) * 2304 + ch, Qs + (wave * 64 + p * 256) * 8);
  }
  float zacc[8];
#pragma unroll
  for (int j = 0; j < 8; ++j) zacc[j] = 0.f;

  for (int lt = 0; lt < 8; ++lt) {
#pragma unroll
    for (int p = 0; p < 4; ++p) {
      int idx = tid + p * 256, row = idx >> 3;
      int ch = ((idx & 7) ^ (row & 7)) * 8;
      async_ld16(kbase + (size_t)(lt * 128 + row) * 2304 + ch, Ks + (wave * 64 + p * 256) * 8);
    }
    __syncthreads();
    f32x4 acc[2][8];
#pragma unroll
    for (int i = 0; i < 2; ++i)
#pragma unroll
      for (int j = 0; j < 8; ++j) acc[i][j] = (f32x4){0.f, 0.f, 0.f, 0.f};
#pragma unroll
    for (int ks = 0; ks < 2; ++ks) {
      bf16x8 af[2], bf[8];
#pragma unroll
      for (int i = 0; i < 2; ++i) {
        int m = wave * 32 + i * 16 + lo;
        int slot = (ks * 4 + quad) ^ (m & 7);
        af[i] = *(const bf16x8*)(Ks + m * 64 + slot * 8);
      }
#pragma unroll
      for (int j = 0; j < 8; ++j) {
        int n = j * 16 + lo;
        int slot = (ks * 4 + quad) ^ (n & 7);
        bf[j] = *(const bf16x8*)(Qs + n * 64 + slot * 8);
      }
#pragma unroll
      for (int i = 0; i < 2; ++i)
#pragma unroll
        for (int j = 0; j < 8; ++j)
          acc[i][j] = __builtin_amdgcn_mfma_f32_16x16x32_bf16(af[i], bf[j], acc[i][j], 0, 0, 0);
    }
#pragma unroll
    for (int j = 0; j < 8; ++j)
#pragma unroll
      for (int i = 0; i < 2; ++i)
#pragma unroll
        for (int r = 0; r < 4; ++r)
          zacc[j] += __expf(acc[i][j][r] * 0.125f);
    __syncthreads();
  }
#pragma unroll
  for (int j = 0; j < 8; ++j) {
    float v = zacc[j];
    v += __shfl_xor(v, 16);
    v += __shfl_xor(v, 32);
    zacc[j] = v;
  }
  if (quad == 0)
#pragma unroll
    for (int j = 0; j < 8; ++j) zred[wave][j * 16 + lo] = zacc[j];
  __syncthreads();
  if (tid < 128) {
    float z = zred[0][tid] + zred[1][tid] + zred[2][tid] + zred[3][tid];
    zinv[(size_t)bh * 1024 + t0 + tid] = 1.0f / z;
  }
}

// --------------- fused attention output -------------------------------------
__global__ __launch_bounds__(256, 2) void attn_out(const u16* __restrict__ tb,
                                                   const u16* __restrict__ vt,
                                                   const float* __restrict__ zinv,
                                                   u16* __restrict__ ao) {
  int bh = blockIdx.y, b = bh / 12, h = bh % 12;
  int l0 = blockIdx.x * 128;
  __shared__ u16 Ks[128 * 64];
  __shared__ u16 Qs[64 * 64];
  __shared__ u16 Vs[64 * 64];
  __shared__ u16 Es[128 * 64];
  int tid = threadIdx.x, wave = tid >> 6, lane = tid & 63;
  int quad = lane >> 4, lo = lane & 15;
  const u16* qbase = tb + (size_t)(b * 1024) * 2304 + h * 64;
  const u16* kbase = qbase + 768;
  const u16* vbase = vt + (size_t)bh * 65536;
  const float* zf = zinv + (size_t)bh * 1024;

#pragma unroll
  for (int p = 0; p < 4; ++p) {
    int idx = tid + p * 256, row = idx >> 3;
    int ch = ((idx & 7) ^ (row & 7)) * 8;
    async_ld16(kbase + (size_t)(l0 + row) * 2304 + ch, Ks + (wave * 64 + p * 256) * 8);
  }
  f32x4 oacc[2][4];
#pragma unroll
  for (int i = 0; i < 2; ++i)
#pragma unroll
    for (int j = 0; j < 4; ++j) oacc[i][j] = (f32x4){0.f, 0.f, 0.f, 0.f};

  for (int tt = 0; tt < 16; ++tt) {
    int t0 = tt * 64;
#pragma unroll
    for (int p = 0; p < 2; ++p) {
      int idx = tid + p * 256, row = idx >> 3;
      int ch = ((idx & 7) ^ (row & 7)) * 8;
      async_ld16(qbase + (size_t)(t0 + row) * 2304 + ch, Qs + (wave * 64 + p * 256) * 8);
      async_ld16(vbase + (size_t)row * 1024 + t0 + ch, Vs + (wave * 64 + p * 256) * 8);
    }
    __syncthreads();
    f32x4 sacc[2][4];
#pragma unroll
    for (int i = 0; i < 2; ++i)
#pragma unroll
      for (int j = 0; j < 4; ++j) sacc[i][j] = (f32x4){0.f, 0.f, 0.f, 0.f};
#pragma unroll
    for (int ks = 0; ks < 2; ++ks) {
      bf16x8 af[2], bq[4];
#pragma unroll
      for (int i = 0; i < 2; ++i) {
        int m = wave * 32 + i * 16 + lo;
        int slot = (ks * 4 + quad) ^ (m & 7);
        af[i] = *(const bf16x8*)(Ks + m * 64 + slot * 8);
      }
#pragma unroll
      for (int j = 0; j < 4; ++j) {
        int n = j * 16 + lo;
        int slot = (ks * 4 + quad) ^ (n & 7);
        bq[j] = *(const bf16x8*)(Qs + n * 64 + slot * 8);
      }
#pragma unroll
      for (int i = 0; i < 2; ++i)
#pragma unroll
        for (int j = 0; j < 4; ++j)
          sacc[i][j] = __builtin_amdgcn_mfma_f32_16x16x32_bf16(af[i], bq[j], sacc[i][j], 0, 0, 0);
    }
#pragma unroll
    for (int j = 0; j < 4; ++j) {
      int t_loc = j * 16 + lo;
      float zi = zf[t0 + t_loc];
      int ch = t_loc >> 3, pos = t_loc & 7;
#pragma unroll
      for (int i = 0; i < 2; ++i)
#pragma unroll
        for (int r = 0; r < 4; ++r) {
          int l_loc = wave * 32 + i * 16 + quad * 4 + r;
          float e = __expf(sacc[i][j][r] * 0.125f) * zi;
          Es[l_loc * 64 + ((ch ^ (l_loc & 7)) * 8 + pos)] = f2bf(e);
        }
    }
#pragma unroll
    for (int ks = 0; ks < 2; ++ks) {
      bf16x8 ae[2], bv[4];
#pragma unroll
      for (int i = 0; i < 2; ++i) {
        int m = wave * 32 + i * 16 + lo;
        int slot = (ks * 4 + quad) ^ (m & 7);
        ae[i] = *(const bf16x8*)(Es + m * 64 + slot * 8);
      }
#pragma unroll
      for (int j = 0; j < 4; ++j) {
        int n = j * 16 + lo;
        int slot = (ks * 4 + quad) ^ (n & 7);
        bv[j] = *(const bf16x8*)(Vs + n * 64 + slot * 8);
      }
#pragma unroll
      for (int i = 0; i < 2; ++i)
#pragma unroll
        for (int j = 0; j < 4; ++j)
          oacc[i][j] = __builtin_amdgcn_mfma_f32_16x16x32_bf16(ae[i], bv[j], oacc[i][j], 0, 0, 0);
    }
    __syncthreads();
  }
#pragma unroll
  for (int j = 0; j < 4; ++j) {
    int c = j * 16 + lo;
#pragma unroll
    for (int i = 0; i < 2; ++i)
#pragma unroll
      for (int r = 0; r < 4; ++r) {
        int l = l0 + wave * 32 + i * 16 + quad * 4 + r;
        ao[(size_t)(b * 1024 + l) * 768 + h * 64 + c] = f2bf(oacc[i][j][r]);
      }
  }
}

// ----------------------------- host orchestration ---------------------------
extern "C" void kernel_launch(void* const* d_in, const int* in_sizes, int n_in,
                              void* d_out, int out_size, void* d_ws, size_t ws_size,
                              hipStream_t stream) {
  const float* x       = (const float*)d_in[0];
  const float* qkv_g   = (const float*)d_in[1];
  const float* qkv_b   = (const float*)d_in[2];
  const float* qkv_W1  = (const float*)d_in[3];
  const float* qkv_b1  = (const float*)d_in[4];
  const float* qkv_W2  = (const float*)d_in[5];
  const float* qkv_b2  = (const float*)d_in[6];
  const float* proj_g  = (const float*)d_in[7];
  const float* proj_b  = (const float*)d_in[8];
  const float* proj_W1 = (const float*)d_in[9];
  const float* proj_b1 = (const float*)d_in[10];
  const float* proj_W2 = (const float*)d_in[11];
  const float* proj_b2 = (const float*)d_in[12];
  const float* mlp_g   = (const float*)d_in[13];
  const float* mlp_b   = (const float*)d_in[14];
  const float* mlp_W1  = (const float*)d_in[15];
  const float* mlp_b1  = (const float*)d_in[16];
  const float* mlp_W2  = (const float*)d_in[17];
  const float* mlp_b2  = (const float*)d_in[18];

  u16* ws  = (u16*)d_ws;               // u16 offsets; ~157 MB total
  u16* xn  = ws;                       // 6291456 (LN out; zinv aliases this)
  u16* tb  = ws + 6291456;             // qkv out 8192x2304
  u16* ao  = ws + 25165824;            // attention out
  u16* yb  = ws + 31457280;            // proj block out
  u16* vt  = ws + 37748736;            // V^T [96][64][1024]
  u16* wt1 = ws + 44040192;            // W1^T bf16
  u16* wt2 = ws + 46399488;            // W2^T bf16
  u16* hS  = ws + 53477376;            // hidden 8192x3072
  float* zinv = (float*)xn;            // 96*1024 floats, aliases dead xn
  float* Pf  = (float*)tb;             // split-K partials 2x8192x768 fp32

  // ---- qkv block ----
  transpose_f32_bf16<<<dim3(96, 24), dim3(32, 8), 0, stream>>>(qkv_W1, wt1, 768, 3072);
  transpose_f32_bf16<<<dim3(72, 96), dim3(32, 8), 0, stream>>>(qkv_W2, wt2, 3072, 2304);
  ln_kernel<<<8192, 256, 0, stream>>>(x, qkv_g, qkv_b, xn, 1);
  gemm_256<<<dim3(12, 32), dim3(512), 0, stream>>>(
      xn, 768, wt1, 768, hS, 3072, 12, qkv_b1, 1);
  gemm_256<<<dim3(9, 32), dim3(512), 0, stream>>>(
      hS, 3072, wt2, 3072, tb, 2304, 48, qkv_b2, 0);

  // ---- attention (fused) ----
  vtrans<<<dim3(32, 2, 96), dim3(32, 8), 0, stream>>>(tb, vt);
  zstats<<<dim3(8, 96), dim3(256), 0, stream>>>(tb, zinv);
  attn_out<<<dim3(8, 96), dim3(256), 0, stream>>>(tb, vt, zinv, ao);

  // ---- proj block ----
  transpose_f32_bf16<<<dim3(96, 24), dim3(32, 8), 0, stream>>>(proj_W1, wt1, 768, 3072);
  transpose_f32_bf16<<<dim3(24, 96), dim3(32, 8), 0, stream>>>(proj_W2, wt2, 3072, 768);
  ln_kernel<<<8192, 256, 0, stream>>>(ao, proj_g, proj_b, xn, 0);
  gemm_256<<<dim3(12, 32), dim3(512), 0, stream>>>(
      xn, 768, wt1, 768, hS, 3072, 12, proj_b1, 1);
  gemm_mfma<<<dim3(6, 64, 2), dim3(256), 0, stream>>>(
      hS, 3072, wt2, 3072, Pf, 768, 8192, 768, 1536, proj_b2, 0, 1, PHALF);

  // ---- mlp block ----
  transpose_f32_bf16<<<dim3(96, 24), dim3(32, 8), 0, stream>>>(mlp_W1, wt1, 768, 3072);
  transpose_f32_bf16<<<dim3(24, 96), dim3(32, 8), 0, stream>>>(mlp_W2, wt2, 3072, 768);
  ln_kernel<<<8192, 256, 0, stream>>>(Pf, mlp_g, mlp_b, xn, 2);  // combines P0+P1
  gemm_256<<<dim3(12, 32), dim3(512), 0, stream>>>(
      xn, 768, wt1, 768, hS, 3072, 12, mlp_b1, 1);
  gemm_mfma<<<dim3(6, 64, 2), dim3(256), 0, stream>>>(
      hS, 3072, wt2, 3072, Pf, 768, 8192, 768, 1536, mlp_b2, 0, 1, PHALF);
  add2_kernel<<<6144, 256, 0, stream>>>(Pf, (float*)d_out);
}

// Round 3
// 711.871 us; speedup vs baseline: 1.2865x; 1.1301x over previous
//
#include <hip/hip_runtime.h>
#include <stdint.h>

// ---------------------------------------------------------------------------
// TransformerBlock: 3x (LN -> FC(768,3072) -> GELU -> FC(3072,N)) + attention.
// fp32 in/out, bf16 MFMA compute with fp32 acc.
// Round-7 changes (consolidation):
//  (1) REVERT all GEMMs to the round-0 gemm_mfma 128^2 path (proven 147 us
//      FC2-qkv / 715 us total). The 256^2 8-phase port measured 44% in-block
//      MFMA efficiency x a 2.0-round tail (288 blocks @ 1 block/CU) = 188 us;
//      even the template's 62% would only reach ~133 us here. Grid
//      granularity on these shapes defeats the 256^2 structure.
//  (2) zstats/attn_out: __launch_bounds__(256,2) -> (256,3). LDS (34/48 KB)
//      allows 3 blocks/CU; the old VGPR cap was the only blocker. 768-block
//      grids now fill the machine exactly (no 1.5-round tail) + 50% more
//      waves/CU to hide exp/LDS latency between QK and PV MFMA clusters.
// ---------------------------------------------------------------------------

typedef unsigned short u16;
typedef __attribute__((ext_vector_type(8))) short bf16x8;
typedef __attribute__((ext_vector_type(4))) float f32x4;
typedef __attribute__((address_space(1))) unsigned int as1_u32;
typedef __attribute__((address_space(3))) unsigned int as3_u32;

#define PHALF 6291456  // fp32 elements per split-K partial buffer (8192*768)

__device__ __forceinline__ float bf2f(u16 u) {
  union { unsigned int i; float f; } v; v.i = ((unsigned int)u) << 16; return v.f;
}
__device__ __forceinline__ u16 f2bf(float f) {
  union { float f; unsigned int i; } v; v.f = f;
  unsigned int r = v.i + 0x7fffu + ((v.i >> 16) & 1u);  // RNE
  return (u16)(r >> 16);
}
__device__ __forceinline__ float gelu_exact(float x) {
  return 0.5f * x * (1.0f + erff(x * 0.70710678118654752f));
}
__device__ __forceinline__ void async_ld16(const u16* g, u16* l) {
  __builtin_amdgcn_global_load_lds((const as1_u32*)g, (as3_u32*)l, 16, 0, 0);
}

// ------------------- LayerNorm (per token, C=768) -> bf16 -------------------
// inMode: 0 = bf16 rows, 1 = fp32 rows, 2 = sum of two fp32 partial buffers.
__global__ __launch_bounds__(256) void ln_kernel(const void* __restrict__ xv,
                                                 const float* __restrict__ g,
                                                 const float* __restrict__ be,
                                                 u16* __restrict__ out, int inMode) {
  int token = blockIdx.x, tid = threadIdx.x;
  int wave = tid >> 6, lane = tid & 63;
  float v0, v1, v2;
  if (inMode == 1) {
    const float* row = (const float*)xv + (size_t)token * 768;
    v0 = row[tid]; v1 = row[tid + 256]; v2 = row[tid + 512];
  } else if (inMode == 2) {
    const float* row = (const float*)xv + (size_t)token * 768;
    const float* row2 = row + PHALF;
    v0 = row[tid] + row2[tid];
    v1 = row[tid + 256] + row2[tid + 256];
    v2 = row[tid + 512] + row2[tid + 512];
  } else {
    const u16* row = (const u16*)xv + (size_t)token * 768;
    v0 = bf2f(row[tid]); v1 = bf2f(row[tid + 256]); v2 = bf2f(row[tid + 512]);
  }
  float s = v0 + v1 + v2;
  float q = v0 * v0 + v1 * v1 + v2 * v2;
#pragma unroll
  for (int m = 1; m < 64; m <<= 1) { s += __shfl_xor(s, m); q += __shfl_xor(q, m); }
  __shared__ float red[8];
  if (lane == 0) { red[wave] = s; red[4 + wave] = q; }
  __syncthreads();
  s = red[0] + red[1] + red[2] + red[3];
  q = red[4] + red[5] + red[6] + red[7];
  float mean = s * (1.0f / 768.0f);
  float var  = q * (1.0f / 768.0f) - mean * mean;
  float inv  = rsqrtf(var + 1e-5f);
  u16* o = out + (size_t)token * 768;
  o[tid]       = f2bf((v0 - mean) * inv * g[tid]       + be[tid]);
  o[tid + 256] = f2bf((v1 - mean) * inv * g[tid + 256] + be[tid + 256]);
  o[tid + 512] = f2bf((v2 - mean) * inv * g[tid + 512] + be[tid + 512]);
}

// ------------- fp32 (R x C) -> bf16 transposed (C x R) ----------------------
__global__ __launch_bounds__(256) void transpose_f32_bf16(const float* __restrict__ in,
                                                          u16* __restrict__ out,
                                                          int R, int Cc) {
  __shared__ u16 tile[32][33];
  int c0 = blockIdx.x * 32, r0 = blockIdx.y * 32;
  int tx = threadIdx.x, ty = threadIdx.y;  // 32 x 8
  for (int i = ty; i < 32; i += 8)
    tile[i][tx] = f2bf(in[(size_t)(r0 + i) * Cc + c0 + tx]);
  __syncthreads();
  for (int i = ty; i < 32; i += 8)
    out[(size_t)(c0 + i) * R + r0 + tx] = tile[tx][i];
}

// ------------- V transpose: t(token, 1536 + h*64 + c) -> vt[bh][c][t] -------
__global__ __launch_bounds__(256) void vtrans(const u16* __restrict__ t,
                                              u16* __restrict__ vt) {
  int bh = blockIdx.z, b = bh / 12, h = bh % 12;
  int t0 = blockIdx.x * 32, c0 = blockIdx.y * 32;
  __shared__ u16 tile[32][33];
  int tx = threadIdx.x, ty = threadIdx.y;
  for (int i = ty; i < 32; i += 8)
    tile[i][tx] = t[(size_t)(b * 1024 + t0 + i) * 2304 + 1536 + h * 64 + c0 + tx];
  __syncthreads();
  for (int i = ty; i < 32; i += 8)
    vt[(size_t)bh * 65536 + (size_t)(c0 + i) * 1024 + t0 + tx] = tile[tx][i];
}

// -------------------- add2: out = P0 + P1 (split-K combine) -----------------
__global__ __launch_bounds__(256) void add2_kernel(const float* __restrict__ P,
                                                   float* __restrict__ out) {
  int idx = blockIdx.x * 256 + threadIdx.x;   // f32x4 index, n/4 = 1572864
  const f32x4* p0 = (const f32x4*)P;
  const f32x4* p1 = (const f32x4*)(P + PHALF);
  ((f32x4*)out)[idx] = p0[idx] + p1[idx];
}

// ----------------------------- MFMA GEMM (FC layers) ------------------------
// kSplit = K handled per z-slice (kOff = z*kSplit). cF32: fp32 C (partials at
// z*cZStride). Bias applied only on z==0. XCD row-band swizzle when gy%8==0.
#define BM 128
#define BN 128
#define BKK 64

__global__ __launch_bounds__(256, 4) void gemm_mfma(
    const u16* __restrict__ A, int lda,
    const u16* __restrict__ B, int ldb,
    void* __restrict__ C, int ldc,
    int M, int N, int kSplit,
    const float* __restrict__ bias, int act, int cF32, long long cZStride) {
  __shared__ u16 As[BM * BKK];
  __shared__ u16 Bs[BN * BKK];
  // XCD row-banded tile mapping: lin%8 = XCD (round-robin dispatch); XCD x
  // owns row band [x*gy/8, (x+1)*gy/8), col-fastest within band.
  int gx = gridDim.x, gy = gridDim.y;
  int bx, by;
  if ((gy & 7) == 0) {
    int lin = blockIdx.y * gx + blockIdx.x;
    int xcd = lin & 7, s = lin >> 3;
    int r = s / gx;
    by = xcd * (gy >> 3) + r;
    bx = s - r * gx;
  } else { bx = blockIdx.x; by = blockIdx.y; }
  int m0 = by * BM, n0 = bx * BN;
  int kOff = blockIdx.z * kSplit;
  int tid = threadIdx.x;
  int wave = tid >> 6, lane = tid & 63;
  int quad = lane >> 4, lo = lane & 15;
  int wr = (wave >> 1) * 64, wc = (wave & 1) * 64;

  f32x4 acc[4][4];
#pragma unroll
  for (int i = 0; i < 4; ++i)
#pragma unroll
    for (int j = 0; j < 4; ++j) acc[i][j] = (f32x4){0.f, 0.f, 0.f, 0.f};

  for (int k0 = kOff; k0 < kOff + kSplit; k0 += BKK) {
    // XOR-swizzled staging: lane(row,slot) fetches global chunk slot^(row&7)
#pragma unroll
    for (int p = 0; p < 4; ++p) {
      int idx = tid + p * 256;
      int row = idx >> 3;
      int gch = ((idx & 7) ^ (row & 7)) * 8;
      int ldsOff = (wave * 64 + p * 256) * 8;
      async_ld16(A + (long long)(m0 + row) * lda + k0 + gch, As + ldsOff);
      async_ld16(B + (long long)(n0 + row) * ldb + k0 + gch, Bs + ldsOff);
    }
    __syncthreads();
#pragma unroll
    for (int ks = 0; ks < 2; ++ks) {
      bf16x8 af[4], bf[4];
#pragma unroll
      for (int i = 0; i < 4; ++i) {
        int m = wr + i * 16 + lo;
        int slot = (ks * 4 + quad) ^ (m & 7);
        af[i] = *(const bf16x8*)(As + m * BKK + slot * 8);
      }
#pragma unroll
      for (int j = 0; j < 4; ++j) {
        int n = wc + j * 16 + lo;
        int slot = (ks * 4 + quad) ^ (n & 7);
        bf[j] = *(const bf16x8*)(Bs + n * BKK + slot * 8);
      }
#pragma unroll
      for (int i = 0; i < 4; ++i)
#pragma unroll
        for (int j = 0; j < 4; ++j)
          acc[i][j] = __builtin_amdgcn_mfma_f32_16x16x32_bf16(af[i], bf[j], acc[i][j], 0, 0, 0);
    }
    __syncthreads();
  }

  // C/D layout: col = lane&15, row = quad*4+reg.
  long long cZ = (long long)blockIdx.z * cZStride;
#pragma unroll
  for (int j = 0; j < 4; ++j) {
    int col = n0 + wc + j * 16 + lo;
    float bv = (bias && blockIdx.z == 0) ? bias[col] : 0.0f;
#pragma unroll
    for (int i = 0; i < 4; ++i) {
      int rb = m0 + wr + i * 16 + quad * 4;
#pragma unroll
      for (int r = 0; r < 4; ++r) {
        int row = rb + r;
        float v = acc[i][j][r] + bv;
        if (act) v = gelu_exact(v);
        long long ci = cZ + (long long)row * ldc + col;
        if (cF32) ((float*)C)[ci] = v;
        else      ((u16*)C)[ci] = f2bf(v);
      }
    }
  }
}

// --------------- zstats: invZ[t] = 1 / sum_l exp(0.125*K[l].Q[t]) -----------
// grid (8 t-blocks, 96 bh), block 256. tb holds qkv output rows of 2304.
// LDS 34 KB -> 3 blocks/CU (102 KB); 768-block grid fills machine exactly.
__global__ __launch_bounds__(256, 3) void zstats(const u16* __restrict__ tb,
                                                 float* __restrict__ zinv) {
  int bh = blockIdx.y, b = bh / 12, h = bh % 12;
  int t0 = blockIdx.x * 128;
  __shared__ u16 Qs[128 * 64];
  __shared__ u16 Ks[128 * 64];
  __shared__ float zred[4][128];
  int tid = threadIdx.x, wave = tid >> 6, lane = tid & 63;
  int quad = lane >> 4, lo = lane & 15;
  const u16* qbase = tb + (size_t)(b * 1024) * 2304 + h * 64;
  const u16* kbase = qbase + 768;

#pragma unroll
  for (int p = 0; p < 4; ++p) {
    int idx = tid + p * 256, row = idx >> 3;
    int ch = ((idx & 7) ^ (row & 7)) * 8;
    async_ld16(qbase + (size_t)(t0 + row) * 2304 + ch, Qs + (wave * 64 + p * 256) * 8);
  }
  float zacc[8];
#pragma unroll
  for (int j = 0; j < 8; ++j) zacc[j] = 0.f;

  for (int lt = 0; lt < 8; ++lt) {
#pragma unroll
    for (int p = 0; p < 4; ++p) {
      int idx = tid + p * 256, row = idx >> 3;
      int ch = ((idx & 7) ^ (row & 7)) * 8;
      async_ld16(kbase + (size_t)(lt * 128 + row) * 2304 + ch, Ks + (wave * 64 + p * 256) * 8);
    }
    __syncthreads();
    f32x4 acc[2][8];
#pragma unroll
    for (int i = 0; i < 2; ++i)
#pragma unroll
      for (int j = 0; j < 8; ++j) acc[i][j] = (f32x4){0.f, 0.f, 0.f, 0.f};
#pragma unroll
    for (int ks = 0; ks < 2; ++ks) {
      bf16x8 af[2], bf[8];
#pragma unroll
      for (int i = 0; i < 2; ++i) {
        int m = wave * 32 + i * 16 + lo;
        int slot = (ks * 4 + quad) ^ (m & 7);
        af[i] = *(const bf16x8*)(Ks + m * 64 + slot * 8);
      }
#pragma unroll
      for (int j = 0; j < 8; ++j) {
        int n = j * 16 + lo;
        int slot = (ks * 4 + quad) ^ (n & 7);
        bf[j] = *(const bf16x8*)(Qs + n * 64 + slot * 8);
      }
#pragma unroll
      for (int i = 0; i < 2; ++i)
#pragma unroll
        for (int j = 0; j < 8; ++j)
          acc[i][j] = __builtin_amdgcn_mfma_f32_16x16x32_bf16(af[i], bf[j], acc[i][j], 0, 0, 0);
    }
#pragma unroll
    for (int j = 0; j < 8; ++j)
#pragma unroll
      for (int i = 0; i < 2; ++i)
#pragma unroll
        for (int r = 0; r < 4; ++r)
          zacc[j] += __expf(acc[i][j][r] * 0.125f);
    __syncthreads();
  }
#pragma unroll
  for (int j = 0; j < 8; ++j) {
    float v = zacc[j];
    v += __shfl_xor(v, 16);
    v += __shfl_xor(v, 32);
    zacc[j] = v;
  }
  if (quad == 0)
#pragma unroll
    for (int j = 0; j < 8; ++j) zred[wave][j * 16 + lo] = zacc[j];
  __syncthreads();
  if (tid < 128) {
    float z = zred[0][tid] + zred[1][tid] + zred[2][tid] + zred[3][tid];
    zinv[(size_t)bh * 1024 + t0 + tid] = 1.0f / z;
  }
}

// --------------- fused attention output -------------------------------------
// out[l][c] = sum_t exp(0.125*K[l].Q[t]) * invZ[t] * V[t][c]
// grid (8 l-blocks, 96 bh). LDS: K-tile(16K) Q(8K) V(8K) E(16K) = 48 KB
// -> 3 blocks/CU (144 KB); 768-block grid fills machine exactly.
__global__ __launch_bounds__(256, 3) void attn_out(const u16* __restrict__ tb,
                                                   const u16* __restrict__ vt,
                                                   const float* __restrict__ zinv,
                                                   u16* __restrict__ ao) {
  int bh = blockIdx.y, b = bh / 12, h = bh % 12;
  int l0 = blockIdx.x * 128;
  __shared__ u16 Ks[128 * 64];
  __shared__ u16 Qs[64 * 64];
  __shared__ u16 Vs[64 * 64];
  __shared__ u16 Es[128 * 64];
  int tid = threadIdx.x, wave = tid >> 6, lane = tid & 63;
  int quad = lane >> 4, lo = lane & 15;
  const u16* qbase = tb + (size_t)(b * 1024) * 2304 + h * 64;
  const u16* kbase = qbase + 768;
  const u16* vbase = vt + (size_t)bh * 65536;
  const float* zf = zinv + (size_t)bh * 1024;

#pragma unroll
  for (int p = 0; p < 4; ++p) {
    int idx = tid + p * 256, row = idx >> 3;
    int ch = ((idx & 7) ^ (row & 7)) * 8;
    async_ld16(kbase + (size_t)(l0 + row) * 2304 + ch, Ks + (wave * 64 + p * 256) * 8);
  }
  f32x4 oacc[2][4];
#pragma unroll
  for (int i = 0; i < 2; ++i)
#pragma unroll
    for (int j = 0; j < 4; ++j) oacc[i][j] = (f32x4){0.f, 0.f, 0.f, 0.f};

  for (int tt = 0; tt < 16; ++tt) {
    int t0 = tt * 64;
#pragma unroll
    for (int p = 0; p < 2; ++p) {
      int idx = tid + p * 256, row = idx >> 3;
      int ch = ((idx & 7) ^ (row & 7)) * 8;
      async_ld16(qbase + (size_t)(t0 + row) * 2304 + ch, Qs + (wave * 64 + p * 256) * 8);
      async_ld16(vbase + (size_t)row * 1024 + t0 + ch, Vs + (wave * 64 + p * 256) * 8);
    }
    __syncthreads();
    // S-tile: 128 l x 64 t
    f32x4 sacc[2][4];
#pragma unroll
    for (int i = 0; i < 2; ++i)
#pragma unroll
      for (int j = 0; j < 4; ++j) sacc[i][j] = (f32x4){0.f, 0.f, 0.f, 0.f};
#pragma unroll
    for (int ks = 0; ks < 2; ++ks) {
      bf16x8 af[2], bq[4];
#pragma unroll
      for (int i = 0; i < 2; ++i) {
        int m = wave * 32 + i * 16 + lo;
        int slot = (ks * 4 + quad) ^ (m & 7);
        af[i] = *(const bf16x8*)(Ks + m * 64 + slot * 8);
      }
#pragma unroll
      for (int j = 0; j < 4; ++j) {
        int n = j * 16 + lo;
        int slot = (ks * 4 + quad) ^ (n & 7);
        bq[j] = *(const bf16x8*)(Qs + n * 64 + slot * 8);
      }
#pragma unroll
      for (int i = 0; i < 2; ++i)
#pragma unroll
        for (int j = 0; j < 4; ++j)
          sacc[i][j] = __builtin_amdgcn_mfma_f32_16x16x32_bf16(af[i], bq[j], sacc[i][j], 0, 0, 0);
    }
    // E = exp(S)*invZ -> Es (rows are wave-local: no barrier needed)
#pragma unroll
    for (int j = 0; j < 4; ++j) {
      int t_loc = j * 16 + lo;
      float zi = zf[t0 + t_loc];
      int ch = t_loc >> 3, pos = t_loc & 7;
#pragma unroll
      for (int i = 0; i < 2; ++i)
#pragma unroll
        for (int r = 0; r < 4; ++r) {
          int l_loc = wave * 32 + i * 16 + quad * 4 + r;
          float e = __expf(sacc[i][j][r] * 0.125f) * zi;
          Es[l_loc * 64 + ((ch ^ (l_loc & 7)) * 8 + pos)] = f2bf(e);
        }
    }
    // out += E(128x64) @ V^T(64t x 64c)
#pragma unroll
    for (int ks = 0; ks < 2; ++ks) {
      bf16x8 ae[2], bv[4];
#pragma unroll
      for (int i = 0; i < 2; ++i) {
        int m = wave * 32 + i * 16 + lo;
        int slot = (ks * 4 + quad) ^ (m & 7);
        ae[i] = *(const bf16x8*)(Es + m * 64 + slot * 8);
      }
#pragma unroll
      for (int j = 0; j < 4; ++j) {
        int n = j * 16 + lo;
        int slot = (ks * 4 + quad) ^ (n & 7);
        bv[j] = *(const bf16x8*)(Vs + n * 64 + slot * 8);
      }
#pragma unroll
      for (int i = 0; i < 2; ++i)
#pragma unroll
        for (int j = 0; j < 4; ++j)
          oacc[i][j] = __builtin_amdgcn_mfma_f32_16x16x32_bf16(ae[i], bv[j], oacc[i][j], 0, 0, 0);
    }
    __syncthreads();
  }
#pragma unroll
  for (int j = 0; j < 4; ++j) {
    int c = j * 16 + lo;
#pragma unroll
    for (int i = 0; i < 2; ++i)
#pragma unroll
      for (int r = 0; r < 4; ++r) {
        int l = l0 + wave * 32 + i * 16 + quad * 4 + r;
        ao[(size_t)(b * 1024 + l) * 768 + h * 64 + c] = f2bf(oacc[i][j][r]);
      }
  }
}

// ----------------------------- host orchestration ---------------------------
extern "C" void kernel_launch(void* const* d_in, const int* in_sizes, int n_in,
                              void* d_out, int out_size, void* d_ws, size_t ws_size,
                              hipStream_t stream) {
  const float* x       = (const float*)d_in[0];
  const float* qkv_g   = (const float*)d_in[1];
  const float* qkv_b   = (const float*)d_in[2];
  const float* qkv_W1  = (const float*)d_in[3];
  const float* qkv_b1  = (const float*)d_in[4];
  const float* qkv_W2  = (const float*)d_in[5];
  const float* qkv_b2  = (const float*)d_in[6];
  const float* proj_g  = (const float*)d_in[7];
  const float* proj_b  = (const float*)d_in[8];
  const float* proj_W1 = (const float*)d_in[9];
  const float* proj_b1 = (const float*)d_in[10];
  const float* proj_W2 = (const float*)d_in[11];
  const float* proj_b2 = (const float*)d_in[12];
  const float* mlp_g   = (const float*)d_in[13];
  const float* mlp_b   = (const float*)d_in[14];
  const float* mlp_W1  = (const float*)d_in[15];
  const float* mlp_b1  = (const float*)d_in[16];
  const float* mlp_W2  = (const float*)d_in[17];
  const float* mlp_b2  = (const float*)d_in[18];

  u16* ws  = (u16*)d_ws;               // u16 offsets; ~157 MB total
  u16* xn  = ws;                       // 6291456 (LN out; zinv aliases this)
  u16* tb  = ws + 6291456;             // qkv out 8192x2304
  u16* ao  = ws + 25165824;            // attention out
  u16* yb  = ws + 31457280;            // proj block out
  u16* vt  = ws + 37748736;            // V^T [96][64][1024]
  u16* wt1 = ws + 44040192;            // W1^T bf16
  u16* wt2 = ws + 46399488;            // W2^T bf16
  u16* hS  = ws + 53477376;            // hidden 8192x3072
  float* zinv = (float*)xn;            // 96*1024 floats, aliases dead xn
  float* Pf  = (float*)tb;             // split-K partials 2x8192x768 fp32,
                                       // aliases dead tb+ao (50.3 MB exactly)

  // ---- qkv block ----
  transpose_f32_bf16<<<dim3(96, 24), dim3(32, 8), 0, stream>>>(qkv_W1, wt1, 768, 3072);
  transpose_f32_bf16<<<dim3(72, 96), dim3(32, 8), 0, stream>>>(qkv_W2, wt2, 3072, 2304);
  ln_kernel<<<8192, 256, 0, stream>>>(x, qkv_g, qkv_b, xn, 1);
  gemm_mfma<<<dim3(24, 64), dim3(256), 0, stream>>>(
      xn, 768, wt1, 768, hS, 3072, 8192, 3072, 768, qkv_b1, 1, 0, 0);
  gemm_mfma<<<dim3(18, 64), dim3(256), 0, stream>>>(
      hS, 3072, wt2, 3072, tb, 2304, 8192, 2304, 3072, qkv_b2, 0, 0, 0);

  // ---- attention (fused) ----
  vtrans<<<dim3(32, 2, 96), dim3(32, 8), 0, stream>>>(tb, vt);
  zstats<<<dim3(8, 96), dim3(256), 0, stream>>>(tb, zinv);
  attn_out<<<dim3(8, 96), dim3(256), 0, stream>>>(tb, vt, zinv, ao);

  // ---- proj block ----
  transpose_f32_bf16<<<dim3(96, 24), dim3(32, 8), 0, stream>>>(proj_W1, wt1, 768, 3072);
  transpose_f32_bf16<<<dim3(24, 96), dim3(32, 8), 0, stream>>>(proj_W2, wt2, 3072, 768);
  ln_kernel<<<8192, 256, 0, stream>>>(ao, proj_g, proj_b, xn, 0);
  gemm_mfma<<<dim3(24, 64), dim3(256), 0, stream>>>(
      xn, 768, wt1, 768, hS, 3072, 8192, 3072, 768, proj_b1, 1, 0, 0);
  // split-K=2: z in {0,1}, each 1536; fp32 partials (tb/ao dead here)
  gemm_mfma<<<dim3(6, 64, 2), dim3(256), 0, stream>>>(
      hS, 3072, wt2, 3072, Pf, 768, 8192, 768, 1536, proj_b2, 0, 1, PHALF);

  // ---- mlp block ----
  transpose_f32_bf16<<<dim3(96, 24), dim3(32, 8), 0, stream>>>(mlp_W1, wt1, 768, 3072);
  transpose_f32_bf16<<<dim3(24, 96), dim3(32, 8), 0, stream>>>(mlp_W2, wt2, 3072, 768);
  ln_kernel<<<8192, 256, 0, stream>>>(Pf, mlp_g, mlp_b, xn, 2);  // combines P0+P1
  gemm_mfma<<<dim3(24, 64), dim3(256), 0, stream>>>(
      xn, 768, wt1, 768, hS, 3072, 8192, 3072, 768, mlp_b1, 1, 0, 0);
  gemm_mfma<<<dim3(6, 64, 2), dim3(256), 0, stream>>>(
      hS, 3072, wt2, 3072, Pf, 768, 8192, 768, 1536, mlp_b2, 0, 1, PHALF);
  add2_kernel<<<6144, 256, 0, stream>>>(Pf, (float*)d_out);
}

// Round 4
// 691.025 us; speedup vs baseline: 1.3253x; 1.0302x over previous
//
#include <hip/hip_runtime.h>
#include <stdint.h>

// ---------------------------------------------------------------------------
// TransformerBlock: 3x (LN -> FC(768,3072) -> GELU -> FC(3072,N)) + attention.
// fp32 in/out, bf16 MFMA compute with fp32 acc.
// Round-8 changes (attention E-phase de-tax; GEMMs untouched at their
// structural ceiling):
//  (1) zstats now runs BEFORE vtrans; vtrans folds zinv into V
//      (V'[t][c] = zinv[t]*V[t][c], bf16) -- attn_out no longer needs zinv.
//  (2) attn_out computes S^T via swapped MFMA operands (m=t, n=l): each
//      lane's C-fragment holds 4 CONSECUTIVE t for fixed l, which packs
//      into one ds_write_b64 (chunk-half of the XOR swizzle). E-phase goes
//      from 32 ds_write_b16 + 4 zi loads + 32 mults per lane/tt to
//      8 ds_write_b64 + 32 exps. PV cluster unchanged.
// ---------------------------------------------------------------------------

typedef unsigned short u16;
typedef __attribute__((ext_vector_type(8))) short bf16x8;
typedef __attribute__((ext_vector_type(4))) float f32x4;
typedef __attribute__((ext_vector_type(4))) unsigned short u16x4;
typedef __attribute__((address_space(1))) unsigned int as1_u32;
typedef __attribute__((address_space(3))) unsigned int as3_u32;

#define PHALF 6291456  // fp32 elements per split-K partial buffer (8192*768)

__device__ __forceinline__ float bf2f(u16 u) {
  union { unsigned int i; float f; } v; v.i = ((unsigned int)u) << 16; return v.f;
}
__device__ __forceinline__ u16 f2bf(float f) {
  union { float f; unsigned int i; } v; v.f = f;
  unsigned int r = v.i + 0x7fffu + ((v.i >> 16) & 1u);  // RNE
  return (u16)(r >> 16);
}
__device__ __forceinline__ float gelu_exact(float x) {
  return 0.5f * x * (1.0f + erff(x * 0.70710678118654752f));
}
__device__ __forceinline__ void async_ld16(const u16* g, u16* l) {
  __builtin_amdgcn_global_load_lds((const as1_u32*)g, (as3_u32*)l, 16, 0, 0);
}

// ------------------- LayerNorm (per token, C=768) -> bf16 -------------------
// inMode: 0 = bf16 rows, 1 = fp32 rows, 2 = sum of two fp32 partial buffers.
__global__ __launch_bounds__(256) void ln_kernel(const void* __restrict__ xv,
                                                 const float* __restrict__ g,
                                                 const float* __restrict__ be,
                                                 u16* __restrict__ out, int inMode) {
  int token = blockIdx.x, tid = threadIdx.x;
  int wave = tid >> 6, lane = tid & 63;
  float v0, v1, v2;
  if (inMode == 1) {
    const float* row = (const float*)xv + (size_t)token * 768;
    v0 = row[tid]; v1 = row[tid + 256]; v2 = row[tid + 512];
  } else if (inMode == 2) {
    const float* row = (const float*)xv + (size_t)token * 768;
    const float* row2 = row + PHALF;
    v0 = row[tid] + row2[tid];
    v1 = row[tid + 256] + row2[tid + 256];
    v2 = row[tid + 512] + row2[tid + 512];
  } else {
    const u16* row = (const u16*)xv + (size_t)token * 768;
    v0 = bf2f(row[tid]); v1 = bf2f(row[tid + 256]); v2 = bf2f(row[tid + 512]);
  }
  float s = v0 + v1 + v2;
  float q = v0 * v0 + v1 * v1 + v2 * v2;
#pragma unroll
  for (int m = 1; m < 64; m <<= 1) { s += __shfl_xor(s, m); q += __shfl_xor(q, m); }
  __shared__ float red[8];
  if (lane == 0) { red[wave] = s; red[4 + wave] = q; }
  __syncthreads();
  s = red[0] + red[1] + red[2] + red[3];
  q = red[4] + red[5] + red[6] + red[7];
  float mean = s * (1.0f / 768.0f);
  float var  = q * (1.0f / 768.0f) - mean * mean;
  float inv  = rsqrtf(var + 1e-5f);
  u16* o = out + (size_t)token * 768;
  o[tid]       = f2bf((v0 - mean) * inv * g[tid]       + be[tid]);
  o[tid + 256] = f2bf((v1 - mean) * inv * g[tid + 256] + be[tid + 256]);
  o[tid + 512] = f2bf((v2 - mean) * inv * g[tid + 512] + be[tid + 512]);
}

// ------------- fp32 (R x C) -> bf16 transposed (C x R) ----------------------
__global__ __launch_bounds__(256) void transpose_f32_bf16(const float* __restrict__ in,
                                                          u16* __restrict__ out,
                                                          int R, int Cc) {
  __shared__ u16 tile[32][33];
  int c0 = blockIdx.x * 32, r0 = blockIdx.y * 32;
  int tx = threadIdx.x, ty = threadIdx.y;  // 32 x 8
  for (int i = ty; i < 32; i += 8)
    tile[i][tx] = f2bf(in[(size_t)(r0 + i) * Cc + c0 + tx]);
  __syncthreads();
  for (int i = ty; i < 32; i += 8)
    out[(size_t)(c0 + i) * R + r0 + tx] = tile[tx][i];
}

// ------------- V transpose + zinv fold: vt[bh][c][t] = V[t][c]*zinv[t] ------
__global__ __launch_bounds__(256) void vtrans(const u16* __restrict__ t,
                                              const float* __restrict__ zinv,
                                              u16* __restrict__ vt) {
  int bh = blockIdx.z, b = bh / 12, h = bh % 12;
  int t0 = blockIdx.x * 32, c0 = blockIdx.y * 32;
  __shared__ u16 tile[32][33];
  int tx = threadIdx.x, ty = threadIdx.y;
  for (int i = ty; i < 32; i += 8) {
    float zi = zinv[(size_t)bh * 1024 + t0 + i];
    float v = bf2f(t[(size_t)(b * 1024 + t0 + i) * 2304 + 1536 + h * 64 + c0 + tx]);
    tile[i][tx] = f2bf(v * zi);
  }
  __syncthreads();
  for (int i = ty; i < 32; i += 8)
    vt[(size_t)bh * 65536 + (size_t)(c0 + i) * 1024 + t0 + tx] = tile[tx][i];
}

// -------------------- add2: out = P0 + P1 (split-K combine) -----------------
__global__ __launch_bounds__(256) void add2_kernel(const float* __restrict__ P,
                                                   float* __restrict__ out) {
  int idx = blockIdx.x * 256 + threadIdx.x;   // f32x4 index, n/4 = 1572864
  const f32x4* p0 = (const f32x4*)P;
  const f32x4* p1 = (const f32x4*)(P + PHALF);
  ((f32x4*)out)[idx] = p0[idx] + p1[idx];
}

// ----------------------------- MFMA GEMM (FC layers) ------------------------
// kSplit = K handled per z-slice (kOff = z*kSplit). cF32: fp32 C (partials at
// z*cZStride). Bias applied only on z==0. XCD row-band swizzle when gy%8==0.
#define BM 128
#define BN 128
#define BKK 64

__global__ __launch_bounds__(256, 4) void gemm_mfma(
    const u16* __restrict__ A, int lda,
    const u16* __restrict__ B, int ldb,
    void* __restrict__ C, int ldc,
    int M, int N, int kSplit,
    const float* __restrict__ bias, int act, int cF32, long long cZStride) {
  __shared__ u16 As[BM * BKK];
  __shared__ u16 Bs[BN * BKK];
  // XCD row-banded tile mapping: lin%8 = XCD (round-robin dispatch); XCD x
  // owns row band [x*gy/8, (x+1)*gy/8), col-fastest within band.
  int gx = gridDim.x, gy = gridDim.y;
  int bx, by;
  if ((gy & 7) == 0) {
    int lin = blockIdx.y * gx + blockIdx.x;
    int xcd = lin & 7, s = lin >> 3;
    int r = s / gx;
    by = xcd * (gy >> 3) + r;
    bx = s - r * gx;
  } else { bx = blockIdx.x; by = blockIdx.y; }
  int m0 = by * BM, n0 = bx * BN;
  int kOff = blockIdx.z * kSplit;
  int tid = threadIdx.x;
  int wave = tid >> 6, lane = tid & 63;
  int quad = lane >> 4, lo = lane & 15;
  int wr = (wave >> 1) * 64, wc = (wave & 1) * 64;

  f32x4 acc[4][4];
#pragma unroll
  for (int i = 0; i < 4; ++i)
#pragma unroll
    for (int j = 0; j < 4; ++j) acc[i][j] = (f32x4){0.f, 0.f, 0.f, 0.f};

  for (int k0 = kOff; k0 < kOff + kSplit; k0 += BKK) {
    // XOR-swizzled staging: lane(row,slot) fetches global chunk slot^(row&7)
#pragma unroll
    for (int p = 0; p < 4; ++p) {
      int idx = tid + p * 256;
      int row = idx >> 3;
      int gch = ((idx & 7) ^ (row & 7)) * 8;
      int ldsOff = (wave * 64 + p * 256) * 8;
      async_ld16(A + (long long)(m0 + row) * lda + k0 + gch, As + ldsOff);
      async_ld16(B + (long long)(n0 + row) * ldb + k0 + gch, Bs + ldsOff);
    }
    __syncthreads();
#pragma unroll
    for (int ks = 0; ks < 2; ++ks) {
      bf16x8 af[4], bf[4];
#pragma unroll
      for (int i = 0; i < 4; ++i) {
        int m = wr + i * 16 + lo;
        int slot = (ks * 4 + quad) ^ (m & 7);
        af[i] = *(const bf16x8*)(As + m * BKK + slot * 8);
      }
#pragma unroll
      for (int j = 0; j < 4; ++j) {
        int n = wc + j * 16 + lo;
        int slot = (ks * 4 + quad) ^ (n & 7);
        bf[j] = *(const bf16x8*)(Bs + n * BKK + slot * 8);
      }
#pragma unroll
      for (int i = 0; i < 4; ++i)
#pragma unroll
        for (int j = 0; j < 4; ++j)
          acc[i][j] = __builtin_amdgcn_mfma_f32_16x16x32_bf16(af[i], bf[j], acc[i][j], 0, 0, 0);
    }
    __syncthreads();
  }

  // C/D layout: col = lane&15, row = quad*4+reg.
  long long cZ = (long long)blockIdx.z * cZStride;
#pragma unroll
  for (int j = 0; j < 4; ++j) {
    int col = n0 + wc + j * 16 + lo;
    float bv = (bias && blockIdx.z == 0) ? bias[col] : 0.0f;
#pragma unroll
    for (int i = 0; i < 4; ++i) {
      int rb = m0 + wr + i * 16 + quad * 4;
#pragma unroll
      for (int r = 0; r < 4; ++r) {
        int row = rb + r;
        float v = acc[i][j][r] + bv;
        if (act) v = gelu_exact(v);
        long long ci = cZ + (long long)row * ldc + col;
        if (cF32) ((float*)C)[ci] = v;
        else      ((u16*)C)[ci] = f2bf(v);
      }
    }
  }
}

// --------------- zstats: invZ[t] = 1 / sum_l exp(0.125*K[l].Q[t]) -----------
// grid (8 t-blocks, 96 bh), block 256. tb holds qkv output rows of 2304.
// LDS 34 KB -> 3 blocks/CU (102 KB); 768-block grid fills machine exactly.
__global__ __launch_bounds__(256, 3) void zstats(const u16* __restrict__ tb,
                                                 float* __restrict__ zinv) {
  int bh = blockIdx.y, b = bh / 12, h = bh % 12;
  int t0 = blockIdx.x * 128;
  __shared__ u16 Qs[128 * 64];
  __shared__ u16 Ks[128 * 64];
  __shared__ float zred[4][128];
  int tid = threadIdx.x, wave = tid >> 6, lane = tid & 63;
  int quad = lane >> 4, lo = lane & 15;
  const u16* qbase = tb + (size_t)(b * 1024) * 2304 + h * 64;
  const u16* kbase = qbase + 768;

#pragma unroll
  for (int p = 0; p < 4; ++p) {
    int idx = tid + p * 256, row = idx >> 3;
    int ch = ((idx & 7) ^ (row & 7)) * 8;
    async_ld16(qbase + (size_t)(t0 + row) * 2304 + ch, Qs + (wave * 64 + p * 256) * 8);
  }
  float zacc[8];
#pragma unroll
  for (int j = 0; j < 8; ++j) zacc[j] = 0.f;

  for (int lt = 0; lt < 8; ++lt) {
#pragma unroll
    for (int p = 0; p < 4; ++p) {
      int idx = tid + p * 256, row = idx >> 3;
      int ch = ((idx & 7) ^ (row & 7)) * 8;
      async_ld16(kbase + (size_t)(lt * 128 + row) * 2304 + ch, Ks + (wave * 64 + p * 256) * 8);
    }
    __syncthreads();
    f32x4 acc[2][8];
#pragma unroll
    for (int i = 0; i < 2; ++i)
#pragma unroll
      for (int j = 0; j < 8; ++j) acc[i][j] = (f32x4){0.f, 0.f, 0.f, 0.f};
#pragma unroll
    for (int ks = 0; ks < 2; ++ks) {
      bf16x8 af[2], bf[8];
#pragma unroll
      for (int i = 0; i < 2; ++i) {
        int m = wave * 32 + i * 16 + lo;
        int slot = (ks * 4 + quad) ^ (m & 7);
        af[i] = *(const bf16x8*)(Ks + m * 64 + slot * 8);
      }
#pragma unroll
      for (int j = 0; j < 8; ++j) {
        int n = j * 16 + lo;
        int slot = (ks * 4 + quad) ^ (n & 7);
        bf[j] = *(const bf16x8*)(Qs + n * 64 + slot * 8);
      }
#pragma unroll
      for (int i = 0; i < 2; ++i)
#pragma unroll
        for (int j = 0; j < 8; ++j)
          acc[i][j] = __builtin_amdgcn_mfma_f32_16x16x32_bf16(af[i], bf[j], acc[i][j], 0, 0, 0);
    }
#pragma unroll
    for (int j = 0; j < 8; ++j)
#pragma unroll
      for (int i = 0; i < 2; ++i)
#pragma unroll
        for (int r = 0; r < 4; ++r)
          zacc[j] += __expf(acc[i][j][r] * 0.125f);
    __syncthreads();
  }
#pragma unroll
  for (int j = 0; j < 8; ++j) {
    float v = zacc[j];
    v += __shfl_xor(v, 16);
    v += __shfl_xor(v, 32);
    zacc[j] = v;
  }
  if (quad == 0)
#pragma unroll
    for (int j = 0; j < 8; ++j) zred[wave][j * 16 + lo] = zacc[j];
  __syncthreads();
  if (tid < 128) {
    float z = zred[0][tid] + zred[1][tid] + zred[2][tid] + zred[3][tid];
    zinv[(size_t)bh * 1024 + t0 + tid] = 1.0f / z;
  }
}

// --------------- fused attention output -------------------------------------
// out[l][c] = sum_t exp(0.125*K[l].Q[t]) * V'[t][c], V' pre-scaled by zinv.
// grid (8 l-blocks, 96 bh). LDS: K-tile(16K) Q(8K) V(8K) E(16K) = 48 KB
// -> 3 blocks/CU (144 KB); 768-block grid fills machine exactly.
// QK^T computed SWAPPED (m=t, n=l): lane holds 4 consecutive t per l ->
// E-store is one packed ds_write_b64 per (i,j) into the XOR-swizzled Es.
__global__ __launch_bounds__(256, 3) void attn_out(const u16* __restrict__ tb,
                                                   const u16* __restrict__ vt,
                                                   u16* __restrict__ ao) {
  int bh = blockIdx.y, b = bh / 12, h = bh % 12;
  int l0 = blockIdx.x * 128;
  __shared__ u16 Ks[128 * 64];
  __shared__ u16 Qs[64 * 64];
  __shared__ u16 Vs[64 * 64];
  __shared__ u16 Es[128 * 64];
  int tid = threadIdx.x, wave = tid >> 6, lane = tid & 63;
  int quad = lane >> 4, lo = lane & 15;
  const u16* qbase = tb + (size_t)(b * 1024) * 2304 + h * 64;
  const u16* kbase = qbase + 768;
  const u16* vbase = vt + (size_t)bh * 65536;

#pragma unroll
  for (int p = 0; p < 4; ++p) {
    int idx = tid + p * 256, row = idx >> 3;
    int ch = ((idx & 7) ^ (row & 7)) * 8;
    async_ld16(kbase + (size_t)(l0 + row) * 2304 + ch, Ks + (wave * 64 + p * 256) * 8);
  }
  f32x4 oacc[2][4];
#pragma unroll
  for (int i = 0; i < 2; ++i)
#pragma unroll
    for (int j = 0; j < 4; ++j) oacc[i][j] = (f32x4){0.f, 0.f, 0.f, 0.f};

  for (int tt = 0; tt < 16; ++tt) {
    int t0 = tt * 64;
#pragma unroll
    for (int p = 0; p < 2; ++p) {
      int idx = tid + p * 256, row = idx >> 3;
      int ch = ((idx & 7) ^ (row & 7)) * 8;
      async_ld16(qbase + (size_t)(t0 + row) * 2304 + ch, Qs + (wave * 64 + p * 256) * 8);
      async_ld16(vbase + (size_t)row * 1024 + t0 + ch, Vs + (wave * 64 + p * 256) * 8);
    }
    __syncthreads();
    // S^T tile: 64 t (m) x 32 l (n, wave-local). 16 MFMA.
    f32x4 sacc[4][2];
#pragma unroll
    for (int i = 0; i < 4; ++i)
#pragma unroll
      for (int j = 0; j < 2; ++j) sacc[i][j] = (f32x4){0.f, 0.f, 0.f, 0.f};
#pragma unroll
    for (int ks = 0; ks < 2; ++ks) {
      bf16x8 aq[4], bk[2];
#pragma unroll
      for (int i = 0; i < 4; ++i) {
        int m = i * 16 + lo;                       // t row
        int slot = (ks * 4 + quad) ^ (m & 7);
        aq[i] = *(const bf16x8*)(Qs + m * 64 + slot * 8);
      }
#pragma unroll
      for (int j = 0; j < 2; ++j) {
        int n = wave * 32 + j * 16 + lo;           // l row
        int slot = (ks * 4 + quad) ^ (n & 7);
        bk[j] = *(const bf16x8*)(Ks + n * 64 + slot * 8);
      }
#pragma unroll
      for (int i = 0; i < 4; ++i)
#pragma unroll
        for (int j = 0; j < 2; ++j)
          sacc[i][j] = __builtin_amdgcn_mfma_f32_16x16x32_bf16(aq[i], bk[j], sacc[i][j], 0, 0, 0);
    }
    // E = exp(0.125*S) -> Es[l][t], packed b64 (4 consecutive t per lane).
    // C layout: col = l offset (lane&15), row = t = i*16 + quad*4 + r.
    // Rows written are wave-local (l in [wave*32, wave*32+32)): no barrier
    // needed before this wave's PV reads.
#pragma unroll
    for (int j = 0; j < 2; ++j) {
      int l = wave * 32 + j * 16 + lo;
#pragma unroll
      for (int i = 0; i < 4; ++i) {
        int ch = 2 * i + (quad >> 1);              // t-chunk index (8 t each)
        int sch = ch ^ (l & 7);                    // swizzled chunk
        u16x4 pk;
#pragma unroll
        for (int r = 0; r < 4; ++r)
          pk[r] = f2bf(__expf(sacc[i][j][r] * 0.125f));
        *(u16x4*)(Es + l * 64 + sch * 8 + (quad & 1) * 4) = pk;
      }
    }
    // out += E(128x64) @ V'^T(64t x 64c)
#pragma unroll
    for (int ks = 0; ks < 2; ++ks) {
      bf16x8 ae[2], bv[4];
#pragma unroll
      for (int i = 0; i < 2; ++i) {
        int m = wave * 32 + i * 16 + lo;
        int slot = (ks * 4 + quad) ^ (m & 7);
        ae[i] = *(const bf16x8*)(Es + m * 64 + slot * 8);
      }
#pragma unroll
      for (int j = 0; j < 4; ++j) {
        int n = j * 16 + lo;
        int slot = (ks * 4 + quad) ^ (n & 7);
        bv[j] = *(const bf16x8*)(Vs + n * 64 + slot * 8);
      }
#pragma unroll
      for (int i = 0; i < 2; ++i)
#pragma unroll
        for (int j = 0; j < 4; ++j)
          oacc[i][j] = __builtin_amdgcn_mfma_f32_16x16x32_bf16(ae[i], bv[j], oacc[i][j], 0, 0, 0);
    }
    __syncthreads();
  }
#pragma unroll
  for (int j = 0; j < 4; ++j) {
    int c = j * 16 + lo;
#pragma unroll
    for (int i = 0; i < 2; ++i)
#pragma unroll
      for (int r = 0; r < 4; ++r) {
        int l = l0 + wave * 32 + i * 16 + quad * 4 + r;
        ao[(size_t)(b * 1024 + l) * 768 + h * 64 + c] = f2bf(oacc[i][j][r]);
      }
  }
}

// ----------------------------- host orchestration ---------------------------
extern "C" void kernel_launch(void* const* d_in, const int* in_sizes, int n_in,
                              void* d_out, int out_size, void* d_ws, size_t ws_size,
                              hipStream_t stream) {
  const float* x       = (const float*)d_in[0];
  const float* qkv_g   = (const float*)d_in[1];
  const float* qkv_b   = (const float*)d_in[2];
  const float* qkv_W1  = (const float*)d_in[3];
  const float* qkv_b1  = (const float*)d_in[4];
  const float* qkv_W2  = (const float*)d_in[5];
  const float* qkv_b2  = (const float*)d_in[6];
  const float* proj_g  = (const float*)d_in[7];
  const float* proj_b  = (const float*)d_in[8];
  const float* proj_W1 = (const float*)d_in[9];
  const float* proj_b1 = (const float*)d_in[10];
  const float* proj_W2 = (const float*)d_in[11];
  const float* proj_b2 = (const float*)d_in[12];
  const float* mlp_g   = (const float*)d_in[13];
  const float* mlp_b   = (const float*)d_in[14];
  const float* mlp_W1  = (const float*)d_in[15];
  const float* mlp_b1  = (const float*)d_in[16];
  const float* mlp_W2  = (const float*)d_in[17];
  const float* mlp_b2  = (const float*)d_in[18];

  u16* ws  = (u16*)d_ws;               // u16 offsets; ~157 MB total
  u16* xn  = ws;                       // 6291456 (LN out; zinv aliases this)
  u16* tb  = ws + 6291456;             // qkv out 8192x2304
  u16* ao  = ws + 25165824;            // attention out
  u16* yb  = ws + 31457280;            // proj block out
  u16* vt  = ws + 37748736;            // V'^T [96][64][1024] (zinv-folded)
  u16* wt1 = ws + 44040192;            // W1^T bf16
  u16* wt2 = ws + 46399488;            // W2^T bf16
  u16* hS  = ws + 53477376;            // hidden 8192x3072
  float* zinv = (float*)xn;            // 96*1024 floats, aliases dead xn
  float* Pf  = (float*)tb;             // split-K partials 2x8192x768 fp32,
                                       // aliases dead tb+ao (50.3 MB exactly)

  // ---- qkv block ----
  transpose_f32_bf16<<<dim3(96, 24), dim3(32, 8), 0, stream>>>(qkv_W1, wt1, 768, 3072);
  transpose_f32_bf16<<<dim3(72, 96), dim3(32, 8), 0, stream>>>(qkv_W2, wt2, 3072, 2304);
  ln_kernel<<<8192, 256, 0, stream>>>(x, qkv_g, qkv_b, xn, 1);
  gemm_mfma<<<dim3(24, 64), dim3(256), 0, stream>>>(
      xn, 768, wt1, 768, hS, 3072, 8192, 3072, 768, qkv_b1, 1, 0, 0);
  gemm_mfma<<<dim3(18, 64), dim3(256), 0, stream>>>(
      hS, 3072, wt2, 3072, tb, 2304, 8192, 2304, 3072, qkv_b2, 0, 0, 0);

  // ---- attention (fused) ----
  zstats<<<dim3(8, 96), dim3(256), 0, stream>>>(tb, zinv);        // before vtrans
  vtrans<<<dim3(32, 2, 96), dim3(32, 8), 0, stream>>>(tb, zinv, vt);
  attn_out<<<dim3(8, 96), dim3(256), 0, stream>>>(tb, vt, ao);

  // ---- proj block ----
  transpose_f32_bf16<<<dim3(96, 24), dim3(32, 8), 0, stream>>>(proj_W1, wt1, 768, 3072);
  transpose_f32_bf16<<<dim3(24, 96), dim3(32, 8), 0, stream>>>(proj_W2, wt2, 3072, 768);
  ln_kernel<<<8192, 256, 0, stream>>>(ao, proj_g, proj_b, xn, 0);
  gemm_mfma<<<dim3(24, 64), dim3(256), 0, stream>>>(
      xn, 768, wt1, 768, hS, 3072, 8192, 3072, 768, proj_b1, 1, 0, 0);
  // split-K=2: z in {0,1}, each 1536; fp32 partials (tb/ao dead here)
  gemm_mfma<<<dim3(6, 64, 2), dim3(256), 0, stream>>>(
      hS, 3072, wt2, 3072, Pf, 768, 8192, 768, 1536, proj_b2, 0, 1, PHALF);

  // ---- mlp block ----
  transpose_f32_bf16<<<dim3(96, 24), dim3(32, 8), 0, stream>>>(mlp_W1, wt1, 768, 3072);
  transpose_f32_bf16<<<dim3(24, 96), dim3(32, 8), 0, stream>>>(mlp_W2, wt2, 3072, 768);
  ln_kernel<<<8192, 256, 0, stream>>>(Pf, mlp_g, mlp_b, xn, 2);  // combines P0+P1
  gemm_mfma<<<dim3(24, 64), dim3(256), 0, stream>>>(
      xn, 768, wt1, 768, hS, 3072, 8192, 3072, 768, mlp_b1, 1, 0, 0);
  gemm_mfma<<<dim3(6, 64, 2), dim3(256), 0, stream>>>(
      hS, 3072, wt2, 3072, Pf, 768, 8192, 768, 1536, mlp_b2, 0, 1, PHALF);
  add2_kernel<<<6144, 256, 0, stream>>>(Pf, (float*)d_out);
}